// Round 12
// baseline (951.303 us; speedup 1.0000x reference)
//
#include <hip/hip_runtime.h>
#include <hip/hip_bf16.h>
#include <hip/hip_fp8.h>
#include <math.h>

typedef short s8v __attribute__((ext_vector_type(8)));
typedef short s4v __attribute__((ext_vector_type(4)));
typedef __bf16 bf8v __attribute__((ext_vector_type(8)));
typedef float f4v __attribute__((ext_vector_type(4)));
typedef long l2v __attribute__((ext_vector_type(2)));
typedef long l4v __attribute__((ext_vector_type(4)));
typedef int i8x __attribute__((ext_vector_type(8)));

#define GLOBAL_AS __attribute__((address_space(1)))
#define LDS_AS __attribute__((address_space(3)))

static __device__ __forceinline__ float bf2f(ushort u) {
  return __builtin_bit_cast(float, (unsigned int)u << 16);
}
static __device__ __forceinline__ ushort f2bf(float f) {
  unsigned int u = __builtin_bit_cast(unsigned int, f);
  u += 0x7FFFu + ((u >> 16) & 1u);
  return (ushort)(u >> 16);
}
static __device__ __forceinline__ unsigned char f2fp8(float f) {
#if __has_builtin(__builtin_amdgcn_cvt_pk_fp8_f32)
  int p = __builtin_amdgcn_cvt_pk_fp8_f32(f, f, 0, false);
  return (unsigned char)(p & 0xFF);
#else
  __hip_fp8_e4m3 v(f);
  return (unsigned char)v.__x;
#endif
}
// fast tanh-gelu with hardware rcp
static __device__ __forceinline__ float gelu_f(float v) {
  float t = v * v;
  float u = v * (0.0356774081f * t + 0.7978845608f);
  float e = __expf(-2.0f * u);
  return v * __builtin_amdgcn_rcpf(1.0f + e);
}
static __device__ __forceinline__ float wave_max_f(float v) {
  #pragma unroll
  for (int o = 32; o >= 1; o >>= 1) v = fmaxf(v, __shfl_xor(v, o));
  return v;
}
static __device__ __forceinline__ float wave_sum_f(float v) {
  #pragma unroll
  for (int o = 32; o >= 1; o >>= 1) v += __shfl_xor(v, o);
  return v;
}
static __device__ __forceinline__ void gload16(const void* g, const void* l) {
  __builtin_amdgcn_global_load_lds(
      (const GLOBAL_AS unsigned int*)g,
      (LDS_AS unsigned int*)l, 16, 0, 0);
}

// ---- weight fp32 -> fp8 e4m3, scaled x8, k-interleaved within 64-groups ----
__global__ void cvt_f32_fp8il(const float* __restrict__ in,
                              unsigned char* __restrict__ out, int n, int kmask) {
  int i = (blockIdx.x * 256 + threadIdx.x) * 4;
  if (i >= n) return;
  float4 v = *(const float4*)(in + i);
  const int k = i & kmask;
  const int r = k & 63;
  const int qq = (r >> 3) & 3, h = (r >> 5) & 1, j = r & 7;
  const long o = (long)(i - r) + qq * 16 + h * 8 + j;
  uchar4 ob;
  ob.x = f2fp8(v.x * 8.f); ob.y = f2fp8(v.y * 8.f);
  ob.z = f2fp8(v.z * 8.f); ob.w = f2fp8(v.w * 8.f);
  *(uchar4*)(out + o) = ob;
}

// ---- W1 -> fp8 with OUTPUT-ROW permutation (contiguous epilogue writes) ----
__global__ void cvt_w1_fp8il(const float* __restrict__ in,
                             unsigned char* __restrict__ out) {
  int i = (blockIdx.x * 256 + threadIdx.x) * 4;   // over 2048*512
  const int ro = i >> 9;
  const int k4 = i & 511;
  const int g = ro >> 6, fr = ro & 63;
  const int L = fr & 15, nn = fr >> 4;
  const int sr = g * 64 + ((L >> 1) & 1) * 32 + (L >> 2) * 8 + (L & 1) * 4 + nn;
  float4 v = *(const float4*)(in + (long)sr * 512 + k4);
  const int r = k4 & 63;
  const int o = (k4 - r) + ((r >> 3) & 3) * 16 + (r >> 5) * 8 + (r & 7);
  uchar4 ob;
  ob.x = f2fp8(v.x * 8.f); ob.y = f2fp8(v.y * 8.f);
  ob.z = f2fp8(v.z * 8.f); ob.w = f2fp8(v.w * 8.f);
  *(uchar4*)(out + (long)ro * 512 + o) = ob;
}

// ---- permuted bias: b1p[g*64+p] = b1[g*64+kc(p)] ----
__global__ void perm_b1(const float* __restrict__ b1, float* __restrict__ b1p) {
  const int p = blockIdx.x * 256 + threadIdx.x;   // 2048
  const int g = p >> 6, r = p & 63;
  const int kc = ((r >> 3) & 1) * 32 + (r >> 4) * 8 + ((r >> 2) & 1) * 4 + (r & 3);
  b1p[p] = b1[g * 64 + kc];
}

// ---------------- 512x512 f32 transpose ----------------
__global__ __launch_bounds__(256) void transpose512(
    const float* __restrict__ in, float* __restrict__ out) {
  __shared__ float t[32][33];
  const int bx = blockIdx.x & 15, by = blockIdx.x >> 4;
  const int tx = threadIdx.x & 31, ty = threadIdx.x >> 5;
  #pragma unroll
  for (int i = 0; i < 4; ++i)
    t[ty + i * 8][tx] = in[(long)(by * 32 + ty + i * 8) * 512 + bx * 32 + tx];
  __syncthreads();
  #pragma unroll
  for (int i = 0; i < 4; ++i)
    out[(long)(bx * 32 + ty + i * 8) * 512 + by * 32 + tx] = t[tx][ty + i * 8];
}

// ---------------- Wqo = Wo @ Wq  (f32 inputs, bf16 out) ----------------
__global__ __launch_bounds__(256) void wqo_kernel(
    const float* __restrict__ Wo, const float* __restrict__ Wq,
    ushort* __restrict__ WqoB)
{
  __shared__ float lO[64][33];
  __shared__ float lQ[32][65];
  const int t = threadIdx.x;
  const int bi = (blockIdx.x & 7) * 64, bj = (blockIdx.x >> 3) * 64;
  float acc[16] = {};
  for (int k0 = 0; k0 < 512; k0 += 32) {
    __syncthreads();
    {
      const int r = t >> 2, c = (t & 3) * 8;
      #pragma unroll
      for (int j = 0; j < 8; ++j) lO[r][c + j] = Wo[(long)(bi + r) * 512 + k0 + c + j];
      const int r2 = t >> 3, c2 = (t & 7) * 8;
      #pragma unroll
      for (int j = 0; j < 8; ++j) lQ[r2][c2 + j] = Wq[(long)(k0 + r2) * 512 + bj + c2 + j];
    }
    __syncthreads();
    const int j = t & 63, ig = t >> 6;
    for (int kk = 0; kk < 32; ++kk) {
      float q = lQ[kk][j];
      #pragma unroll
      for (int ii = 0; ii < 16; ++ii) acc[ii] += lO[ig * 16 + ii][kk] * q;
    }
  }
  const int j = t & 63, ig = t >> 6;
  #pragma unroll
  for (int ii = 0; ii < 16; ++ii)
    WqoB[(long)(bi + ig * 16 + ii) * 512 + bj + j] = f2bf(acc[ii]);
}

// ---------------- wa[h,k] = sum_d qa[h,d] Wq[h*64+d,k]; ca[h] = qa_h . bq_h
__global__ __launch_bounds__(256) void wa_kernel(
    const float* __restrict__ qa, const float* __restrict__ Wq,
    const float* __restrict__ bqv, ushort* __restrict__ waB, float* __restrict__ ca)
{
  __shared__ float ql[64];
  const int h = blockIdx.x;   // 0..15 (8..15 pad)
  const int t = threadIdx.x;
  if (h >= 8) {
    waB[h * 512 + t] = 0; waB[h * 512 + 256 + t] = 0;
    if (t == 0) ca[h] = 0.f;
    return;
  }
  if (t < 64) ql[t] = qa[h * 64 + t];
  __syncthreads();
  #pragma unroll
  for (int half = 0; half < 2; ++half) {
    const int k = half * 256 + t;
    float s = 0;
    for (int dd = 0; dd < 64; ++dd) s += ql[dd] * Wq[(long)(h * 64 + dd) * 512 + k];
    waB[h * 512 + k] = f2bf(s);
  }
  if (t == 0) {
    float s = 0;
    for (int dd = 0; dd < 64; ++dd) s += ql[dd] * bqv[h * 64 + dd];
    ca[h] = s;
  }
}

// ======= fused LN0 + alpha logits ========================================
__global__ __launch_bounds__(256) void ln0_alpha(
    const float* __restrict__ x, const float* __restrict__ gam,
    const float* __restrict__ bet, const float* __restrict__ mask,
    const ushort* __restrict__ waB, const float* __restrict__ ca,
    ushort* __restrict__ out, float* __restrict__ AL)
{
  __shared__ ushort wal[8 * 512];
  const int tid = threadIdx.x, lane = tid & 63, wv = tid >> 6;
  *(s8v*)(wal + tid * 8) = *(const s8v*)(waB + tid * 8);
  *(s8v*)(wal + 2048 + tid * 8) = *(const s8v*)(waB + 2048 + tid * 8);
  const float* gp = gam + lane * 8;
  const float* bp = bet + lane * 8;
  float4 g0 = *(const float4*)gp, g1 = *(const float4*)(gp + 4);
  float4 c0 = *(const float4*)bp, c1 = *(const float4*)(bp + 4);
  const float gg[8] = {g0.x, g0.y, g0.z, g0.w, g1.x, g1.y, g1.z, g1.w};
  const float cc[8] = {c0.x, c0.y, c0.z, c0.w, c1.x, c1.y, c1.z, c1.w};
  __syncthreads();
  const long row0 = (long)blockIdx.x * 16 + wv * 4;
  for (int rr = 0; rr < 4; ++rr) {
    const long row = row0 + rr;
    const float* xp = x + row * 512 + lane * 8;
    float4 a = *(const float4*)xp;
    float4 b = *(const float4*)(xp + 4);
    float s = a.x + a.y + a.z + a.w + b.x + b.y + b.z + b.w;
    float q = a.x*a.x + a.y*a.y + a.z*a.z + a.w*a.w
            + b.x*b.x + b.y*b.y + b.z*b.z + b.w*b.w;
    s = wave_sum_f(s); q = wave_sum_f(q);
    const float m = s * (1.f / 512.f);
    const float var = q * (1.f / 512.f) - m * m;
    const float r = rsqrtf(var + 1e-5f);
    const float mk = mask[row];
    const float xin[8] = {a.x, a.y, a.z, a.w, b.x, b.y, b.z, b.w};
    float of[8];
    s8v o;
    #pragma unroll
    for (int j = 0; j < 8; ++j) {
      of[j] = ((xin[j] - m) * r * gg[j] + cc[j]) * mk;
      o[j] = (short)f2bf(of[j]);
    }
    *(s8v*)(out + row * 512 + lane * 8) = o;
    float dh[8];
    #pragma unroll
    for (int h = 0; h < 8; ++h) {
      s8v wa8 = *(const s8v*)(wal + h * 512 + lane * 8);
      float d = 0.f;
      #pragma unroll
      for (int j = 0; j < 8; ++j) d += of[j] * bf2f((ushort)wa8[j]);
      dh[h] = wave_sum_f(d);
    }
    if (lane == 0) {
      const int bb = (int)(row >> 13);
      const int n = (int)(row & 8191);
      #pragma unroll
      for (int h = 0; h < 8; ++h) {
        float lg = (dh[h] + ca[h]) * 0.125f;
        if (mk == 0.f) lg = -1e30f;
        AL[((long)((bb << 3) + h) << 13) + n] = lg;
      }
    }
  }
}

// ---- LayerNorm (bf16 in) -> fp8 e4m3 out, k-interleaved layout ----------
__global__ __launch_bounds__(256) void ln_rows_fp8il(
    const ushort* __restrict__ x, const float* __restrict__ gam,
    const float* __restrict__ bet, unsigned char* __restrict__ out)
{
  const int tid = threadIdx.x, lane = tid & 63, wv = tid >> 6;
  const long row = (long)blockIdx.x * 4 + wv;
  s8v v = *(const s8v*)(x + row * 512 + lane * 8);
  float xv[8];
  #pragma unroll
  for (int j = 0; j < 8; ++j) xv[j] = bf2f((ushort)v[j]);
  float s = 0.f, q = 0.f;
  #pragma unroll
  for (int j = 0; j < 8; ++j) { s += xv[j]; q += xv[j] * xv[j]; }
  s = wave_sum_f(s); q = wave_sum_f(q);
  float m = s * (1.f / 512.f);
  float var = q * (1.f / 512.f) - m * m;
  float r = rsqrtf(var + 1e-5f);
  const float* gp = gam + lane * 8;
  const float* bp = bet + lane * 8;
  float4 g0 = *(const float4*)gp, g1 = *(const float4*)(gp + 4);
  float4 c0 = *(const float4*)bp, c1 = *(const float4*)(bp + 4);
  float gg[8] = {g0.x, g0.y, g0.z, g0.w, g1.x, g1.y, g1.z, g1.w};
  float cc[8] = {c0.x, c0.y, c0.z, c0.w, c1.x, c1.y, c1.z, c1.w};
  unsigned long long pk = 0;
  #pragma unroll
  for (int j = 0; j < 8; ++j) {
    unsigned char b8 = f2fp8((xv[j] - m) * r * gg[j] + cc[j]);
    pk |= (unsigned long long)b8 << (8 * j);
  }
  *(unsigned long long*)(out + row * 512 + (lane >> 3) * 64
                         + (lane & 3) * 16 + ((lane >> 2) & 1) * 8) = pk;
}

// ======= beta logits via MFMA, LDS-staged coalesced XN reads =============
template<int BS, int CS>
__global__ __launch_bounds__(256) void logits_k(
    const ushort* __restrict__ XN, const ushort* __restrict__ Wl,
    const float* __restrict__ cvec, const float* __restrict__ mask,
    float* __restrict__ outL)
{
  __shared__ ushort lw[16 * 512];
  __shared__ __align__(16) ushort lx[64 * 512];
  const int tid = threadIdx.x, lane = tid & 63, wv = tid >> 6;
  const long r0 = (long)blockIdx.x * 64;
  const int b = (int)(r0 >> 13);
  #pragma unroll
  for (int i = 0; i < 16; ++i) {
    const int U = i * 256 + tid;
    const int r = U >> 6, u1 = U & 63;
    const int us = u1 ^ (r & 7);
    gload16(XN + (r0 + r) * 512 + us * 8, lx + (long)U * 8);
  }
  #pragma unroll
  for (int i = 0; i < 4; ++i) {
    const int u = tid + i * 256;
    const int h2 = u >> 6, uu = u & 63;
    s8v v = *(const s8v*)(Wl + (long)b * BS + h2 * 512 + uu * 8);
    *(s8v*)(lw + h2 * 512 + (uu ^ (h2 & 7)) * 8) = v;
  }
  __syncthreads();
  const int h = lane & 15, q = lane >> 4;
  const int rloc = wv * 16 + (lane & 15);
  const ushort* axp = lx + rloc * 512;
  f4v acc = {};
  #pragma unroll
  for (int t = 0; t < 16; ++t) {
    bf8v a = *(const bf8v*)(axp + (((t * 4 + q) ^ (rloc & 7))) * 8);
    bf8v bb = *(const bf8v*)(lw + h * 512 + (((t * 4 + q) ^ (h & 7))) * 8);
    acc = __builtin_amdgcn_mfma_f32_16x16x32_bf16(a, bb, acc, 0, 0, 0);
  }
  const float cv = cvec[b * CS + h];
  const long rw = r0 + wv * 16;
  #pragma unroll
  for (int j = 0; j < 4; ++j) {
    const long n = rw + q * 4 + j;
    float v = (acc[j] + cv) * 0.125f;
    if (mask[n] == 0.f) v = -1e30f;
    if (h < 8) outL[((long)((b << 3) + h) << 13) + (n & 8191)] = v;
  }
}

// ---------------- softmax over N=8192 per (b,h), in place ----------------
__global__ __launch_bounds__(1024) void softmax_rows(float* __restrict__ L)
{
  __shared__ float red[16];
  __shared__ float bc;
  const int tid = threadIdx.x, lane = tid & 63, wv = tid >> 6;
  float* p = L + ((long)blockIdx.x << 13) + tid * 8;
  float4 v0 = *(float4*)p;
  float4 v1 = *(float4*)(p + 4);
  float m = fmaxf(fmaxf(fmaxf(v0.x, v0.y), fmaxf(v0.z, v0.w)),
                  fmaxf(fmaxf(v1.x, v1.y), fmaxf(v1.z, v1.w)));
  m = wave_max_f(m);
  if (lane == 0) red[wv] = m;
  __syncthreads();
  if (tid < 64) {
    float t = (lane < 16) ? red[lane] : -INFINITY;
    t = wave_max_f(t);
    if (lane == 0) bc = t;
  }
  __syncthreads();
  const float gm = bc;
  v0.x = __expf(v0.x - gm); v0.y = __expf(v0.y - gm);
  v0.z = __expf(v0.z - gm); v0.w = __expf(v0.w - gm);
  v1.x = __expf(v1.x - gm); v1.y = __expf(v1.y - gm);
  v1.z = __expf(v1.z - gm); v1.w = __expf(v1.w - gm);
  float s = v0.x + v0.y + v0.z + v0.w + v1.x + v1.y + v1.z + v1.w;
  s = wave_sum_f(s);
  __syncthreads();
  if (lane == 0) red[wv] = s;
  __syncthreads();
  if (tid < 64) {
    float t = (lane < 16) ? red[lane] : 0.f;
    t = wave_sum_f(t);
    if (lane == 0) bc = t;
  }
  __syncthreads();
  const float inv = 1.0f / bc;
  v0.x *= inv; v0.y *= inv; v0.z *= inv; v0.w *= inv;
  v1.x *= inv; v1.y *= inv; v1.z *= inv; v1.w *= inv;
  *(float4*)p = v0;
  *(float4*)(p + 4) = v1;
}

// ---------------- weighted pool partials ----------------
__global__ __launch_bounds__(256) void pool_w(
    const ushort* __restrict__ XN, const float* __restrict__ wbuf,
    float* __restrict__ part)
{
  __shared__ float wlds[128][8];
  __shared__ float cmb[4][512];
  const int tid = threadIdx.x;
  const int b = blockIdx.x >> 6, ch = blockIdx.x & 63;
  const long g0 = ((long)b << 13) + ch * 128;
  if (tid < 128) {
    #pragma unroll
    for (int h = 0; h < 8; ++h)
      wlds[tid][h] = wbuf[(((long)(b * 8 + h)) << 13) + ch * 128 + tid];
  }
  __syncthreads();
  const int rg = tid >> 6, c8 = (tid & 63) * 8;
  f4v acc[8][2] = {};
  for (int it = 0; it < 32; ++it) {
    const int r = it * 4 + rg;
    s8v xv = *(const s8v*)(XN + (g0 + r) * 512 + c8);
    float xf[8];
    #pragma unroll
    for (int j = 0; j < 8; ++j) xf[j] = bf2f((ushort)xv[j]);
    #pragma unroll
    for (int h = 0; h < 8; ++h) {
      const float w = wlds[r][h];
      #pragma unroll
      for (int j = 0; j < 8; ++j) acc[h][j >> 2][j & 3] += w * xf[j];
    }
  }
  #pragma unroll
  for (int h = 0; h < 8; ++h) {
    __syncthreads();
    #pragma unroll
    for (int j = 0; j < 8; ++j) cmb[rg][c8 + j] = acc[h][j >> 2][j & 3];
    __syncthreads();
    const int col = tid * 2;
    float s0 = cmb[0][col] + cmb[1][col] + cmb[2][col] + cmb[3][col];
    float s1 = cmb[0][col + 1] + cmb[1][col + 1] + cmb[2][col + 1] + cmb[3][col + 1];
    *(float2*)(part + (((long)blockIdx.x * 8 + h) << 9) + col) = make_float2(s0, s1);
  }
}

// ======= combine partials + prep1 (gq -> wb/cb), one block per bh ========
__global__ __launch_bounds__(256) void combine_prep1(
    const float* __restrict__ part, const float* __restrict__ WqT,
    const float* __restrict__ bqv, const float* __restrict__ kbv,
    const float* __restrict__ Wk, const float* __restrict__ bkv,
    ushort* __restrict__ wbB, float* __restrict__ cbs)
{
  __shared__ float pxl[512];
  __shared__ float gkb[64];
  const int bh = blockIdx.x, b = bh >> 3, h = bh & 7;
  const int tid = threadIdx.x;
  {
    const int col = tid * 2;
    float s0 = 0.f, s1 = 0.f;
    for (int ch = 0; ch < 64; ++ch) {
      const float* p = part + (((long)((b * 64 + ch) * 8 + h)) << 9) + col;
      s0 += p[0]; s1 += p[1];
    }
    pxl[col] = s0; pxl[col + 1] = s1;
  }
  __syncthreads();
  if (tid < 64) {
    const int d = tid;
    float acc = bqv[h * 64 + d];
    for (int c = 0; c < 512; ++c) acc += pxl[c] * WqT[(long)c * 512 + h * 64 + d];
    gkb[d] = acc * kbv[h * 64 + d];
  }
  __syncthreads();
  if (tid < 64) {
    const int d = tid;
    float s[8] = {};
    for (int dd = 0; dd < 64; ++dd) {
      const float g = gkb[dd];
      const float* wr = Wk + (long)(h * 64 + dd) * 512 + d;
      #pragma unroll
      for (int ki = 0; ki < 8; ++ki) s[ki] += g * wr[ki * 64];
    }
    #pragma unroll
    for (int ki = 0; ki < 8; ++ki)
      wbB[(long)(b * 16 + h) * 512 + d + ki * 64] = f2bf(s[ki]);
    if (d == 0) {
      float t = 0.f;
      for (int dd = 0; dd < 64; ++dd) t += gkb[dd] * bkv[h * 64 + dd];
      cbs[b * 16 + h] = t;
    }
    if (h == 0) {
      #pragma unroll
      for (int hp = 8; hp < 16; ++hp)
        for (int k = d; k < 512; k += 64) wbB[(long)(b * 16 + hp) * 512 + k] = 0;
      if (d < 8) cbs[b * 16 + 8 + d] = 0.f;
    }
  }
}

// ======= combine partials + prep2 (gv), one block per bh =================
__global__ __launch_bounds__(256) void combine_prep2(
    const float* __restrict__ part, const float* __restrict__ WvT,
    const float* __restrict__ bvv, const float* __restrict__ bqv,
    float* __restrict__ gvb)
{
  __shared__ float pxl[512];
  const int bh = blockIdx.x, b = bh >> 3, h = bh & 7;
  const int tid = threadIdx.x;
  {
    const int col = tid * 2;
    float s0 = 0.f, s1 = 0.f;
    for (int ch = 0; ch < 64; ++ch) {
      const float* p = part + (((long)((b * 64 + ch) * 8 + h)) << 9) + col;
      s0 += p[0]; s1 += p[1];
    }
    pxl[col] = s0; pxl[col + 1] = s1;
  }
  __syncthreads();
  if (tid < 64) {
    const int d = tid;
    float acc = bvv[h * 64 + d] + bqv[h * 64 + d];
    for (int c = 0; c < 512; ++c) acc += pxl[c] * WvT[(long)c * 512 + h * 64 + d];
    gvb[b * 512 + h * 64 + d] = acc;
  }
}

// ---------------- BO2[b][n] = bo[n] + gvb[b]·Wo[n,:] ----------------
__global__ __launch_bounds__(256) void bias_gv(
    const float* __restrict__ gv, const float* __restrict__ Wo,
    const float* __restrict__ bo, float* __restrict__ bo2) {
  const int b = blockIdx.x;
  const int n = blockIdx.y * 256 + threadIdx.x;
  const float* g = gv + b * 512;
  const float* w = Wo + (long)n * 512;
  float acc = 0.f;
  for (int d = 0; d < 512; d += 4) {
    float4 wv4 = *(const float4*)(w + d);
    acc += g[d] * wv4.x + g[d + 1] * wv4.y + g[d + 2] * wv4.z + g[d + 3] * wv4.w;
  }
  bo2[b * 512 + n] = bo[n] + acc;
}

// ======== 128x256 tri-buffered bf16 GEMM (Wqo only) =======================
#define MFMA_(d,a,b) d = __builtin_amdgcn_mfma_f32_16x16x32_bf16(a, b, d, 0, 0, 0)

template<int EPI, int LDA, int NN, int KK>
__global__ __launch_bounds__(512, 4) void gemmP(
    const ushort* __restrict__ A, const ushort* __restrict__ W,
    const float* __restrict__ bias, const void* __restrict__ resid,
    const float* __restrict__ mask, void* __restrict__ Out)
{
  constexpr int NBX = NN / 256;
  constexpr int NT = KK / 32;
  __shared__ __align__(16) ushort lds[3][12288];
  const int tid = threadIdx.x;
  const int lane = tid & 63;
  const int w = tid >> 6;
  const int wm = w >> 2, wn = w & 3;

  const int nwg = gridDim.x;
  const int cpx = nwg >> 3;
  const int wg = (blockIdx.x & 7) * cpx + (blockIdx.x >> 3);
  const int bx = wg % NBX, by = wg / NBX;
  const long bm = (long)by * 128;
  const int bn = bx * 256;

  const int scr = tid >> 2, sls = tid & 3;
  const int akU = ((sls ^ (scr & 3) ^ ((scr >> 2) & 3))) * 8;
  const ushort* asrc = A + (bm + scr) * (long)LDA + akU;
  const int rbe = (scr & 31) + ((scr >> 5) << 6);
  const ushort* besrc = W + (long)(bn + rbe) * KK + akU;
  const ushort* bosrc = W + (long)(bn + rbe + 32) * KK + akU;

#define STG(b_, Tt) { \
    gload16(asrc + (Tt) * 32, &lds[b_][tid * 8]); \
    gload16(besrc + (Tt) * 32, &lds[b_][4096 + tid * 8]); \
    gload16(bosrc + (Tt) * 32, &lds[b_][8192 + tid * 8]); }

  STG(0, 0);
  STG(1, 1);

  f4v acc[4][4] = {};

  const int L = lane & 15, q = lane >> 4;
  const int soff = (q ^ (lane & 3) ^ ((lane >> 2) & 3)) * 8;
  const int abase = (wm * 64 + L) * 32 + soff;
  const int bbase = 4096 + (wn * 32 + L) * 32 + soff;

  asm volatile("s_waitcnt vmcnt(3)" ::: "memory");
  asm volatile("s_barrier" ::: "memory");

  for (int T = 0; T < NT; ++T) {
    const ushort* Lp = &lds[T % 3][0];
    bf8v aR[4], bR[4];
    #pragma unroll
    for (int m = 0; m < 4; ++m) aR[m] = *(const bf8v*)(Lp + abase + m * 512);
    bR[0] = *(const bf8v*)(Lp + bbase);
    bR[1] = *(const bf8v*)(Lp + bbase + 512);
    bR[2] = *(const bf8v*)(Lp + bbase + 4096);
    bR[3] = *(const bf8v*)(Lp + bbase + 4096 + 512);
    if (T + 2 < NT) {
      STG((T + 2) % 3, T + 2);
      asm volatile("s_waitcnt vmcnt(3)" ::: "memory");
    } else {
      asm volatile("s_waitcnt vmcnt(0)" ::: "memory");
    }
    asm volatile("s_barrier" ::: "memory");
    __builtin_amdgcn_s_setprio(1);
    #pragma unroll
    for (int m = 0; m < 4; ++m)
      #pragma unroll
      for (int n = 0; n < 4; ++n)
        MFMA_(acc[m][n], aR[m], bR[n]);
    __builtin_amdgcn_s_setprio(0);
  }
#undef STG

  const int colb = bn + wn * 64 + L;
  const long rowb = bm + wm * 64 + q * 4;
  const float* biasp = bias + ((bm >> 13) << 9);
  #pragma unroll
  for (int m = 0; m < 4; ++m) {
    #pragma unroll
    for (int j = 0; j < 4; ++j) {
      const long row = rowb + m * 16 + j;
      #pragma unroll
      for (int n = 0; n < 4; ++n) {
        const int col = colb + n * 16;
        float v = acc[m][n][j] + biasp[col];
        const long idx = row * (long)NN + col;
        ((ushort*)Out)[idx] = f2bf(v + ((const float*)resid)[idx]);
      }
    }
  }
}

// ======== fp8 x fp8 GEMM, k-interleaved, tri-buffered, MX K=128 MFMA ======
// A fp8 [M,KK] il, W fp8 [NN,KK] il (scaled x8 -> acc*0.125)
// Tiles processed in pairs: even tile fills low 16B of 32B operands, odd
// tile fills high 16B and fires 16 mfma_scale_f32_16x16x128_f8f6f4 (scale=1).
// Correct for ANY internal HW k-order because A and B use identical
// slot->k assignment (bijection argument).
// EPI 7: fp8-il out (channel-permuted W1F) = fp8(gelu(acc/8 + b1p))
// EPI 8: f32 out = (bf2f(resid) + gelu(acc/8 + bias))*mask
template<int EPI, int NN, int KK>
__global__ __launch_bounds__(512, 4) void gemmF8(
    const unsigned char* __restrict__ A, const unsigned char* __restrict__ W,
    const float* __restrict__ bias, const void* __restrict__ resid,
    const float* __restrict__ mask, void* __restrict__ Out)
{
  constexpr int NBX = NN / 256;
  constexpr int NT = KK / 64;
  __shared__ __align__(16) unsigned char lds8[3][24576];
  const int tid = threadIdx.x;
  const int lane = tid & 63;
  const int w = tid >> 6;
  const int wm = w >> 2, wn = w & 3;

  const int nwg = gridDim.x;
  const int cpx = nwg >> 3;
  const int wg = (blockIdx.x & 7) * cpx + (blockIdx.x >> 3);
  const int bx = wg % NBX, by = wg / NBX;
  const long bm = (long)by * 128;
  const int bn = bx * 256;

  const int srow = tid >> 2;
  const int sgu = (tid & 3) ^ ((srow >> 1) & 3);
  const unsigned char* asrc = A + (bm + srow) * (long)KK + sgu * 16;
  const unsigned char* b0src = W + (long)(bn + srow) * KK + sgu * 16;
  const unsigned char* b1src = W + (long)(bn + 128 + srow) * KK + sgu * 16;

#define STG8(bf_, Tt) { \
    gload16(asrc + (Tt) * 64, &lds8[bf_][tid * 16]); \
    gload16(b0src + (Tt) * 64, &lds8[bf_][8192 + tid * 16]); \
    gload16(b1src + (Tt) * 64, &lds8[bf_][16384 + tid * 16]); }

  STG8(0, 0);
  STG8(1, 1);

  f4v acc[4][4] = {};

  const int L = lane & 15, q = lane >> 4;
  const int ua = (q ^ ((L >> 1) & 3)) * 16;
  const int arow = (wm * 64 + L) * 64;
  const int brow = 8192 + (wn * 64 + L) * 64;

  asm volatile("s_waitcnt vmcnt(3)" ::: "memory");
  asm volatile("s_barrier" ::: "memory");

#if __has_builtin(__builtin_amdgcn_mfma_scale_f32_16x16x128_f8f6f4)
  l4v aOp[4], bOp[4];
  for (int T2 = 0; T2 < NT / 2; ++T2) {
    {
      const int T = 2 * T2;
      const unsigned char* Lp = &lds8[T % 3][0];
      #pragma unroll
      for (int m = 0; m < 4; ++m) {
        l2v r = *(const l2v*)(Lp + arow + m * 1024 + ua);
        aOp[m][0] = r[0]; aOp[m][1] = r[1];
      }
      #pragma unroll
      for (int n = 0; n < 4; ++n) {
        l2v r = *(const l2v*)(Lp + brow + n * 1024 + ua);
        bOp[n][0] = r[0]; bOp[n][1] = r[1];
      }
      if (T + 2 < NT) {
        STG8((T + 2) % 3, T + 2);
        asm volatile("s_waitcnt vmcnt(3)" ::: "memory");
      } else {
        asm volatile("s_waitcnt vmcnt(0)" ::: "memory");
      }
      asm volatile("s_barrier" ::: "memory");
    }
    {
      const int T = 2 * T2 + 1;
      const unsigned char* Lp = &lds8[T % 3][0];
      #pragma unroll
      for (int m = 0; m < 4; ++m) {
        l2v r = *(const l2v*)(Lp + arow + m * 1024 + ua);
        aOp[m][2] = r[0]; aOp[m][3] = r[1];
      }
      #pragma unroll
      for (int n = 0; n < 4; ++n) {
        l2v r = *(const l2v*)(Lp + brow + n * 1024 + ua);
        bOp[n][2] = r[0]; bOp[n][3] = r[1];
      }
      if (T + 2 < NT) {
        STG8((T + 2) % 3, T + 2);
        asm volatile("s_waitcnt vmcnt(3)" ::: "memory");
      } else {
        asm volatile("s_waitcnt vmcnt(0)" ::: "memory");
      }
      asm volatile("s_barrier" ::: "memory");
      __builtin_amdgcn_s_setprio(1);
      #pragma unroll
      for (int m = 0; m < 4; ++m) {
        const i8x am = __builtin_bit_cast(i8x, aOp[m]);
        #pragma unroll
        for (int n = 0; n < 4; ++n) {
          acc[m][n] = __builtin_amdgcn_mfma_scale_f32_16x16x128_f8f6f4(
              am, __builtin_bit_cast(i8x, bOp[n]), acc[m][n],
              0, 0, 0, 0x7F7F7F7F, 0, 0x7F7F7F7F);
        }
      }
      __builtin_amdgcn_s_setprio(0);
    }
  }
#else
  for (int T = 0; T < NT; ++T) {
    const unsigned char* Lp = &lds8[T % 3][0];
    l2v aV[4], bV[4];
    #pragma unroll
    for (int m = 0; m < 4; ++m) aV[m] = *(const l2v*)(Lp + arow + m * 1024 + ua);
    #pragma unroll
    for (int n = 0; n < 4; ++n) bV[n] = *(const l2v*)(Lp + brow + n * 1024 + ua);
    if (T + 2 < NT) {
      STG8((T + 2) % 3, T + 2);
      asm volatile("s_waitcnt vmcnt(3)" ::: "memory");
    } else {
      asm volatile("s_waitcnt vmcnt(0)" ::: "memory");
    }
    asm volatile("s_barrier" ::: "memory");
    __builtin_amdgcn_s_setprio(1);
    #pragma unroll
    for (int m = 0; m < 4; ++m)
      #pragma unroll
      for (int n = 0; n < 4; ++n) {
        acc[m][n] = __builtin_amdgcn_mfma_f32_16x16x32_fp8_fp8(
            aV[m][0], bV[n][0], acc[m][n], 0, 0, 0);
        acc[m][n] = __builtin_amdgcn_mfma_f32_16x16x32_fp8_fp8(
            aV[m][1], bV[n][1], acc[m][n], 0, 0, 0);
      }
    __builtin_amdgcn_s_setprio(0);
  }
#endif
#undef STG8

  const long rowb = bm + wm * 64 + q * 4;
  const int gbase = bn + wn * 64;
  if constexpr (EPI == 7) {
    const float4 bp4 = *(const float4*)(bias + gbase + 4 * L);
    #pragma unroll
    for (int m = 0; m < 4; ++m) {
      #pragma unroll
      for (int j = 0; j < 4; ++j) {
        const long row = rowb + m * 16 + j;
        float e0 = gelu_f(acc[m][0][j] * 0.125f + bp4.x);
        float e1 = gelu_f(acc[m][1][j] * 0.125f + bp4.y);
        float e2 = gelu_f(acc[m][2][j] * 0.125f + bp4.z);
        float e3 = gelu_f(acc[m][3][j] * 0.125f + bp4.w);
        unsigned int pw;
#if __has_builtin(__builtin_amdgcn_cvt_pk_fp8_f32)
        int t0 = __builtin_amdgcn_cvt_pk_fp8_f32(e0, e1, 0, false);
        pw = (unsigned int)__builtin_amdgcn_cvt_pk_fp8_f32(e2, e3, t0, true);
#else
        pw = (unsigned int)f2fp8(e0) | ((unsigned int)f2fp8(e1) << 8)
           | ((unsigned int)f2fp8(e2) << 16) | ((unsigned int)f2fp8(e3) << 24);
#endif
        *(unsigned int*)((unsigned char*)Out + row * (long)NN + gbase + 4 * L) = pw;
      }
    }
  } else {
    #pragma unroll
    for (int m = 0; m < 4; ++m) {
      #pragma unroll
      for (int j = 0; j < 4; ++j) {
        const long row = rowb + m * 16 + j;
        const float mk = mask[row];
        #pragma unroll
        for (int n = 0; n < 4; ++n) {
          const int col = gbase + n * 16 + L;
          float v = acc[m][n][j] * 0.125f + bias[col];
          const long idx = row * (long)NN + col;
          ((float*)Out)[idx] =
              (bf2f(((const ushort*)resid)[idx]) + gelu_f(v)) * mk;
        }
      }
    }
  }
}

// ---------------- host ----------------
extern "C" void kernel_launch(void* const* d_in, const int* in_sizes, int n_in,
                              void* d_out, int out_size, void* d_ws, size_t ws_size,
                              hipStream_t stream) {
  const float* x    = (const float*)d_in[0];
  const float* mask = (const float*)d_in[1];
  const float* Wq   = (const float*)d_in[2];
  const float* bq   = (const float*)d_in[3];
  const float* Wk   = (const float*)d_in[4];
  const float* bk   = (const float*)d_in[5];
  const float* Wv   = (const float*)d_in[6];
  const float* bv   = (const float*)d_in[7];
  const float* qa   = (const float*)d_in[8];
  const float* kb   = (const float*)d_in[9];
  const float* Wo   = (const float*)d_in[10];
  const float* bo   = (const float*)d_in[11];
  const float* g0   = (const float*)d_in[12];
  const float* be0  = (const float*)d_in[13];
  const float* g1   = (const float*)d_in[14];
  const float* be1  = (const float*)d_in[15];
  const float* W1   = (const float*)d_in[16];
  const float* b1   = (const float*)d_in[17];
  const float* W2   = (const float*)d_in[18];
  const float* b2   = (const float*)d_in[19];
  float* out = (float*)d_out;

  const int M = 65536;          // B*N
  char* ws = (char*)d_ws;
  const size_t MB = 1024 * 1024;
  ushort* XN  = (ushort*)(ws);                           // [0,64) bf16 ln0 out
  ushort* X1  = (ushort*)(ws + 64 * MB);                 // [64,128) bf16
  unsigned char* XN1F = (unsigned char*)(ws + 128 * MB); // [128,160) fp8 il
  unsigned char* H1F  = (unsigned char*)(ws + 192 * MB); // [192,320) fp8 il
  float*  AL  = (float*)(ws + 320 * MB);                 // 2MB
  float*  BL  = (float*)(ws + 322 * MB);                 // 2MB
  float*  PART= (float*)(ws + 324 * MB);                 // 8MB
  char* base = ws + 448 * MB;
  unsigned char* W1F = (unsigned char*)(base);           // 1MB
  unsigned char* W2F = (unsigned char*)(base + 2 * MB);  // 1MB
  ushort* WqoB = (ushort*)(base + 4 * MB);
  float*  WqT  = (float*)(base + 4 * MB + 512 * 1024);
  float*  WvT  = (float*)(base + 5 * MB + 512 * 1024);
  ushort* waB  = (ushort*)(base + 6 * MB + 512 * 1024);
  ushort* wbB  = (ushort*)(base + 6 * MB + 528 * 1024);
  float*  ca   = (float*)(base + 6 * MB + 656 * 1024);
  float*  cbs  = (float*)(base + 6 * MB + 660 * 1024);
  float*  GVB  = (float*)(base + 6 * MB + 920 * 1024);
  float*  BO2  = (float*)(base + 6 * MB + 936 * 1024);
  float*  B1P  = (float*)(base + 6 * MB + 952 * 1024);   // 8KB

  // ---- weight precompute ----
  cvt_w1_fp8il<<<1024, 256, 0, stream>>>(W1, W1F);
  perm_b1<<<8, 256, 0, stream>>>(b1, B1P);
  cvt_f32_fp8il<<<1024, 256, 0, stream>>>(W2, W2F, 1048576, 2047);
  wqo_kernel<<<64, 256, 0, stream>>>(Wo, Wq, WqoB);
  wa_kernel<<<16, 256, 0, stream>>>(qa, Wq, bq, waB, ca);
  transpose512<<<256, 256, 0, stream>>>(Wq, WqT);
  transpose512<<<256, 256, 0, stream>>>(Wv, WvT);

  // ---- fused LN0 (+mask) + alpha logits ----
  ln0_alpha<<<M / 16, 256, 0, stream>>>(x, g0, be0, mask, waB, ca, XN, AL);

  // ---- stage 1: softmax -> pooled x -> gq/wb ----
  softmax_rows<<<64, 1024, 0, stream>>>(AL);
  pool_w<<<512, 256, 0, stream>>>(XN, AL, PART);
  combine_prep1<<<64, 256, 0, stream>>>(PART, WqT, bq, kb, Wk, bk, wbB, cbs);

  // ---- stage 2: beta logits -> softmax -> pooled x -> gv ----
  logits_k<8192, 16><<<1024, 256, 0, stream>>>(XN, wbB, cbs, mask, BL);
  softmax_rows<<<64, 1024, 0, stream>>>(BL);
  pool_w<<<512, 256, 0, stream>>>(XN, BL, PART);
  combine_prep2<<<64, 256, 0, stream>>>(PART, WvT, bv, bq, GVB);
  bias_gv<<<dim3(8, 2), 256, 0, stream>>>(GVB, Wo, bo, BO2);

  // ---- attention out: X1(bf16) = xn @ Wqo^T + BO2[b] + x ----
  gemmP<5, 512, 512, 512><<<2 * (M / 128), 512, 0, stream>>>(
      XN, WqoB, BO2, x, nullptr, X1);

  // ---- LN1 -> XN1F (fp8, k-interleaved) ----
  ln_rows_fp8il<<<M / 4, 256, 0, stream>>>(X1, g1, be1, XN1F);

  // ---- MLP in fp8 (MX K=128 MFMA): W1 -> H1F; W2 -> out ----
  gemmF8<7, 2048, 512><<<8 * (M / 128), 512, 0, stream>>>(
      XN1F, W1F, B1P, nullptr, nullptr, H1F);
  gemmF8<8, 512, 2048><<<2 * (M / 128), 512, 0, stream>>>(
      H1F, W2F, b2, X1, mask, out);
}

// Round 13
// 577.254 us; speedup vs baseline: 1.6480x; 1.6480x over previous
//
#include <hip/hip_runtime.h>
#include <hip/hip_bf16.h>
#include <hip/hip_fp8.h>
#include <math.h>

typedef short s8v __attribute__((ext_vector_type(8)));
typedef short s4v __attribute__((ext_vector_type(4)));
typedef __bf16 bf8v __attribute__((ext_vector_type(8)));
typedef float f4v __attribute__((ext_vector_type(4)));
typedef long l2v __attribute__((ext_vector_type(2)));
typedef long l4v __attribute__((ext_vector_type(4)));
typedef int i8x __attribute__((ext_vector_type(8)));

#define GLOBAL_AS __attribute__((address_space(1)))
#define LDS_AS __attribute__((address_space(3)))

static __device__ __forceinline__ float bf2f(ushort u) {
  return __builtin_bit_cast(float, (unsigned int)u << 16);
}
static __device__ __forceinline__ ushort f2bf(float f) {
  unsigned int u = __builtin_bit_cast(unsigned int, f);
  u += 0x7FFFu + ((u >> 16) & 1u);
  return (ushort)(u >> 16);
}
static __device__ __forceinline__ unsigned char f2fp8(float f) {
#if __has_builtin(__builtin_amdgcn_cvt_pk_fp8_f32)
  int p = __builtin_amdgcn_cvt_pk_fp8_f32(f, f, 0, false);
  return (unsigned char)(p & 0xFF);
#else
  __hip_fp8_e4m3 v(f);
  return (unsigned char)v.__x;
#endif
}
// fast tanh-gelu with hardware rcp
static __device__ __forceinline__ float gelu_f(float v) {
  float t = v * v;
  float u = v * (0.0356774081f * t + 0.7978845608f);
  float e = __expf(-2.0f * u);
  return v * __builtin_amdgcn_rcpf(1.0f + e);
}
static __device__ __forceinline__ float wave_max_f(float v) {
  #pragma unroll
  for (int o = 32; o >= 1; o >>= 1) v = fmaxf(v, __shfl_xor(v, o));
  return v;
}
static __device__ __forceinline__ float wave_sum_f(float v) {
  #pragma unroll
  for (int o = 32; o >= 1; o >>= 1) v += __shfl_xor(v, o);
  return v;
}
static __device__ __forceinline__ void gload16(const void* g, const void* l) {
  __builtin_amdgcn_global_load_lds(
      (const GLOBAL_AS unsigned int*)g,
      (LDS_AS unsigned int*)l, 16, 0, 0);
}

// ---- weight fp32 -> fp8 e4m3, scaled x8, k-interleaved within 64-groups ----
__global__ void cvt_f32_fp8il(const float* __restrict__ in,
                              unsigned char* __restrict__ out, int n, int kmask) {
  int i = (blockIdx.x * 256 + threadIdx.x) * 4;
  if (i >= n) return;
  float4 v = *(const float4*)(in + i);
  const int k = i & kmask;
  const int r = k & 63;
  const int qq = (r >> 3) & 3, h = (r >> 5) & 1, j = r & 7;
  const long o = (long)(i - r) + qq * 16 + h * 8 + j;
  uchar4 ob;
  ob.x = f2fp8(v.x * 8.f); ob.y = f2fp8(v.y * 8.f);
  ob.z = f2fp8(v.z * 8.f); ob.w = f2fp8(v.w * 8.f);
  *(uchar4*)(out + o) = ob;
}

// ---- W1 -> fp8 with OUTPUT-ROW permutation (contiguous epilogue writes) ----
__global__ void cvt_w1_fp8il(const float* __restrict__ in,
                             unsigned char* __restrict__ out) {
  int i = (blockIdx.x * 256 + threadIdx.x) * 4;   // over 2048*512
  const int ro = i >> 9;
  const int k4 = i & 511;
  const int g = ro >> 6, fr = ro & 63;
  const int L = fr & 15, nn = fr >> 4;
  const int sr = g * 64 + ((L >> 1) & 1) * 32 + (L >> 2) * 8 + (L & 1) * 4 + nn;
  float4 v = *(const float4*)(in + (long)sr * 512 + k4);
  const int r = k4 & 63;
  const int o = (k4 - r) + ((r >> 3) & 3) * 16 + (r >> 5) * 8 + (r & 7);
  uchar4 ob;
  ob.x = f2fp8(v.x * 8.f); ob.y = f2fp8(v.y * 8.f);
  ob.z = f2fp8(v.z * 8.f); ob.w = f2fp8(v.w * 8.f);
  *(uchar4*)(out + (long)ro * 512 + o) = ob;
}

// ---- permuted bias: b1p[g*64+p] = b1[g*64+kc(p)] ----
__global__ void perm_b1(const float* __restrict__ b1, float* __restrict__ b1p) {
  const int p = blockIdx.x * 256 + threadIdx.x;   // 2048
  const int g = p >> 6, r = p & 63;
  const int kc = ((r >> 3) & 1) * 32 + (r >> 4) * 8 + ((r >> 2) & 1) * 4 + (r & 3);
  b1p[p] = b1[g * 64 + kc];
}

// ---------------- 512x512 f32 transpose ----------------
__global__ __launch_bounds__(256) void transpose512(
    const float* __restrict__ in, float* __restrict__ out) {
  __shared__ float t[32][33];
  const int bx = blockIdx.x & 15, by = blockIdx.x >> 4;
  const int tx = threadIdx.x & 31, ty = threadIdx.x >> 5;
  #pragma unroll
  for (int i = 0; i < 4; ++i)
    t[ty + i * 8][tx] = in[(long)(by * 32 + ty + i * 8) * 512 + bx * 32 + tx];
  __syncthreads();
  #pragma unroll
  for (int i = 0; i < 4; ++i)
    out[(long)(bx * 32 + ty + i * 8) * 512 + by * 32 + tx] = t[tx][ty + i * 8];
}

// ---------------- Wqo = Wo @ Wq  (f32 inputs, bf16 out) ----------------
__global__ __launch_bounds__(256) void wqo_kernel(
    const float* __restrict__ Wo, const float* __restrict__ Wq,
    ushort* __restrict__ WqoB)
{
  __shared__ float lO[64][33];
  __shared__ float lQ[32][65];
  const int t = threadIdx.x;
  const int bi = (blockIdx.x & 7) * 64, bj = (blockIdx.x >> 3) * 64;
  float acc[16] = {};
  for (int k0 = 0; k0 < 512; k0 += 32) {
    __syncthreads();
    {
      const int r = t >> 2, c = (t & 3) * 8;
      #pragma unroll
      for (int j = 0; j < 8; ++j) lO[r][c + j] = Wo[(long)(bi + r) * 512 + k0 + c + j];
      const int r2 = t >> 3, c2 = (t & 7) * 8;
      #pragma unroll
      for (int j = 0; j < 8; ++j) lQ[r2][c2 + j] = Wq[(long)(k0 + r2) * 512 + bj + c2 + j];
    }
    __syncthreads();
    const int j = t & 63, ig = t >> 6;
    for (int kk = 0; kk < 32; ++kk) {
      float q = lQ[kk][j];
      #pragma unroll
      for (int ii = 0; ii < 16; ++ii) acc[ii] += lO[ig * 16 + ii][kk] * q;
    }
  }
  const int j = t & 63, ig = t >> 6;
  #pragma unroll
  for (int ii = 0; ii < 16; ++ii)
    WqoB[(long)(bi + ig * 16 + ii) * 512 + bj + j] = f2bf(acc[ii]);
}

// ---------------- wa[h,k] = sum_d qa[h,d] Wq[h*64+d,k]; ca[h] = qa_h . bq_h
__global__ __launch_bounds__(256) void wa_kernel(
    const float* __restrict__ qa, const float* __restrict__ Wq,
    const float* __restrict__ bqv, ushort* __restrict__ waB, float* __restrict__ ca)
{
  __shared__ float ql[64];
  const int h = blockIdx.x;   // 0..15 (8..15 pad)
  const int t = threadIdx.x;
  if (h >= 8) {
    waB[h * 512 + t] = 0; waB[h * 512 + 256 + t] = 0;
    if (t == 0) ca[h] = 0.f;
    return;
  }
  if (t < 64) ql[t] = qa[h * 64 + t];
  __syncthreads();
  #pragma unroll
  for (int half = 0; half < 2; ++half) {
    const int k = half * 256 + t;
    float s = 0;
    for (int dd = 0; dd < 64; ++dd) s += ql[dd] * Wq[(long)(h * 64 + dd) * 512 + k];
    waB[h * 512 + k] = f2bf(s);
  }
  if (t == 0) {
    float s = 0;
    for (int dd = 0; dd < 64; ++dd) s += ql[dd] * bqv[h * 64 + dd];
    ca[h] = s;
  }
}

// ======= fused LN0 + alpha logits ========================================
__global__ __launch_bounds__(256) void ln0_alpha(
    const float* __restrict__ x, const float* __restrict__ gam,
    const float* __restrict__ bet, const float* __restrict__ mask,
    const ushort* __restrict__ waB, const float* __restrict__ ca,
    ushort* __restrict__ out, float* __restrict__ AL)
{
  __shared__ ushort wal[8 * 512];
  const int tid = threadIdx.x, lane = tid & 63, wv = tid >> 6;
  *(s8v*)(wal + tid * 8) = *(const s8v*)(waB + tid * 8);
  *(s8v*)(wal + 2048 + tid * 8) = *(const s8v*)(waB + 2048 + tid * 8);
  const float* gp = gam + lane * 8;
  const float* bp = bet + lane * 8;
  float4 g0 = *(const float4*)gp, g1 = *(const float4*)(gp + 4);
  float4 c0 = *(const float4*)bp, c1 = *(const float4*)(bp + 4);
  const float gg[8] = {g0.x, g0.y, g0.z, g0.w, g1.x, g1.y, g1.z, g1.w};
  const float cc[8] = {c0.x, c0.y, c0.z, c0.w, c1.x, c1.y, c1.z, c1.w};
  __syncthreads();
  const long row0 = (long)blockIdx.x * 16 + wv * 4;
  for (int rr = 0; rr < 4; ++rr) {
    const long row = row0 + rr;
    const float* xp = x + row * 512 + lane * 8;
    float4 a = *(const float4*)xp;
    float4 b = *(const float4*)(xp + 4);
    float s = a.x + a.y + a.z + a.w + b.x + b.y + b.z + b.w;
    float q = a.x*a.x + a.y*a.y + a.z*a.z + a.w*a.w
            + b.x*b.x + b.y*b.y + b.z*b.z + b.w*b.w;
    s = wave_sum_f(s); q = wave_sum_f(q);
    const float m = s * (1.f / 512.f);
    const float var = q * (1.f / 512.f) - m * m;
    const float r = rsqrtf(var + 1e-5f);
    const float mk = mask[row];
    const float xin[8] = {a.x, a.y, a.z, a.w, b.x, b.y, b.z, b.w};
    float of[8];
    s8v o;
    #pragma unroll
    for (int j = 0; j < 8; ++j) {
      of[j] = ((xin[j] - m) * r * gg[j] + cc[j]) * mk;
      o[j] = (short)f2bf(of[j]);
    }
    *(s8v*)(out + row * 512 + lane * 8) = o;
    float dh[8];
    #pragma unroll
    for (int h = 0; h < 8; ++h) {
      s8v wa8 = *(const s8v*)(wal + h * 512 + lane * 8);
      float d = 0.f;
      #pragma unroll
      for (int j = 0; j < 8; ++j) d += of[j] * bf2f((ushort)wa8[j]);
      dh[h] = wave_sum_f(d);
    }
    if (lane == 0) {
      const int bb = (int)(row >> 13);
      const int n = (int)(row & 8191);
      #pragma unroll
      for (int h = 0; h < 8; ++h) {
        float lg = (dh[h] + ca[h]) * 0.125f;
        if (mk == 0.f) lg = -1e30f;
        AL[((long)((bb << 3) + h) << 13) + n] = lg;
      }
    }
  }
}

// ---- LayerNorm (bf16 in) -> fp8 e4m3 out, k-interleaved layout ----------
__global__ __launch_bounds__(256) void ln_rows_fp8il(
    const ushort* __restrict__ x, const float* __restrict__ gam,
    const float* __restrict__ bet, unsigned char* __restrict__ out)
{
  const int tid = threadIdx.x, lane = tid & 63, wv = tid >> 6;
  const long row = (long)blockIdx.x * 4 + wv;
  s8v v = *(const s8v*)(x + row * 512 + lane * 8);
  float xv[8];
  #pragma unroll
  for (int j = 0; j < 8; ++j) xv[j] = bf2f((ushort)v[j]);
  float s = 0.f, q = 0.f;
  #pragma unroll
  for (int j = 0; j < 8; ++j) { s += xv[j]; q += xv[j] * xv[j]; }
  s = wave_sum_f(s); q = wave_sum_f(q);
  float m = s * (1.f / 512.f);
  float var = q * (1.f / 512.f) - m * m;
  float r = rsqrtf(var + 1e-5f);
  const float* gp = gam + lane * 8;
  const float* bp = bet + lane * 8;
  float4 g0 = *(const float4*)gp, g1 = *(const float4*)(gp + 4);
  float4 c0 = *(const float4*)bp, c1 = *(const float4*)(bp + 4);
  float gg[8] = {g0.x, g0.y, g0.z, g0.w, g1.x, g1.y, g1.z, g1.w};
  float cc[8] = {c0.x, c0.y, c0.z, c0.w, c1.x, c1.y, c1.z, c1.w};
  unsigned long long pk = 0;
  #pragma unroll
  for (int j = 0; j < 8; ++j) {
    unsigned char b8 = f2fp8((xv[j] - m) * r * gg[j] + cc[j]);
    pk |= (unsigned long long)b8 << (8 * j);
  }
  *(unsigned long long*)(out + row * 512 + (lane >> 3) * 64
                         + (lane & 3) * 16 + ((lane >> 2) & 1) * 8) = pk;
}

// ======= beta logits via MFMA, LDS-staged coalesced XN reads =============
template<int BS, int CS>
__global__ __launch_bounds__(256) void logits_k(
    const ushort* __restrict__ XN, const ushort* __restrict__ Wl,
    const float* __restrict__ cvec, const float* __restrict__ mask,
    float* __restrict__ outL)
{
  __shared__ ushort lw[16 * 512];
  __shared__ __align__(16) ushort lx[64 * 512];
  const int tid = threadIdx.x, lane = tid & 63, wv = tid >> 6;
  const long r0 = (long)blockIdx.x * 64;
  const int b = (int)(r0 >> 13);
  #pragma unroll
  for (int i = 0; i < 16; ++i) {
    const int U = i * 256 + tid;
    const int r = U >> 6, u1 = U & 63;
    const int us = u1 ^ (r & 7);
    gload16(XN + (r0 + r) * 512 + us * 8, lx + (long)U * 8);
  }
  #pragma unroll
  for (int i = 0; i < 4; ++i) {
    const int u = tid + i * 256;
    const int h2 = u >> 6, uu = u & 63;
    s8v v = *(const s8v*)(Wl + (long)b * BS + h2 * 512 + uu * 8);
    *(s8v*)(lw + h2 * 512 + (uu ^ (h2 & 7)) * 8) = v;
  }
  __syncthreads();
  const int h = lane & 15, q = lane >> 4;
  const int rloc = wv * 16 + (lane & 15);
  const ushort* axp = lx + rloc * 512;
  f4v acc = {};
  #pragma unroll
  for (int t = 0; t < 16; ++t) {
    bf8v a = *(const bf8v*)(axp + (((t * 4 + q) ^ (rloc & 7))) * 8);
    bf8v bb = *(const bf8v*)(lw + h * 512 + (((t * 4 + q) ^ (h & 7))) * 8);
    acc = __builtin_amdgcn_mfma_f32_16x16x32_bf16(a, bb, acc, 0, 0, 0);
  }
  const float cv = cvec[b * CS + h];
  const long rw = r0 + wv * 16;
  #pragma unroll
  for (int j = 0; j < 4; ++j) {
    const long n = rw + q * 4 + j;
    float v = (acc[j] + cv) * 0.125f;
    if (mask[n] == 0.f) v = -1e30f;
    if (h < 8) outL[((long)((b << 3) + h) << 13) + (n & 8191)] = v;
  }
}

// ---------------- softmax over N=8192 per (b,h), in place ----------------
__global__ __launch_bounds__(1024) void softmax_rows(float* __restrict__ L)
{
  __shared__ float red[16];
  __shared__ float bc;
  const int tid = threadIdx.x, lane = tid & 63, wv = tid >> 6;
  float* p = L + ((long)blockIdx.x << 13) + tid * 8;
  float4 v0 = *(float4*)p;
  float4 v1 = *(float4*)(p + 4);
  float m = fmaxf(fmaxf(fmaxf(v0.x, v0.y), fmaxf(v0.z, v0.w)),
                  fmaxf(fmaxf(v1.x, v1.y), fmaxf(v1.z, v1.w)));
  m = wave_max_f(m);
  if (lane == 0) red[wv] = m;
  __syncthreads();
  if (tid < 64) {
    float t = (lane < 16) ? red[lane] : -INFINITY;
    t = wave_max_f(t);
    if (lane == 0) bc = t;
  }
  __syncthreads();
  const float gm = bc;
  v0.x = __expf(v0.x - gm); v0.y = __expf(v0.y - gm);
  v0.z = __expf(v0.z - gm); v0.w = __expf(v0.w - gm);
  v1.x = __expf(v1.x - gm); v1.y = __expf(v1.y - gm);
  v1.z = __expf(v1.z - gm); v1.w = __expf(v1.w - gm);
  float s = v0.x + v0.y + v0.z + v0.w + v1.x + v1.y + v1.z + v1.w;
  s = wave_sum_f(s);
  __syncthreads();
  if (lane == 0) red[wv] = s;
  __syncthreads();
  if (tid < 64) {
    float t = (lane < 16) ? red[lane] : 0.f;
    t = wave_sum_f(t);
    if (lane == 0) bc = t;
  }
  __syncthreads();
  const float inv = 1.0f / bc;
  v0.x *= inv; v0.y *= inv; v0.z *= inv; v0.w *= inv;
  v1.x *= inv; v1.y *= inv; v1.z *= inv; v1.w *= inv;
  *(float4*)p = v0;
  *(float4*)(p + 4) = v1;
}

// ---------------- weighted pool partials ----------------
__global__ __launch_bounds__(256) void pool_w(
    const ushort* __restrict__ XN, const float* __restrict__ wbuf,
    float* __restrict__ part)
{
  __shared__ float wlds[128][8];
  __shared__ float cmb[4][512];
  const int tid = threadIdx.x;
  const int b = blockIdx.x >> 6, ch = blockIdx.x & 63;
  const long g0 = ((long)b << 13) + ch * 128;
  if (tid < 128) {
    #pragma unroll
    for (int h = 0; h < 8; ++h)
      wlds[tid][h] = wbuf[(((long)(b * 8 + h)) << 13) + ch * 128 + tid];
  }
  __syncthreads();
  const int rg = tid >> 6, c8 = (tid & 63) * 8;
  f4v acc[8][2] = {};
  for (int it = 0; it < 32; ++it) {
    const int r = it * 4 + rg;
    s8v xv = *(const s8v*)(XN + (g0 + r) * 512 + c8);
    float xf[8];
    #pragma unroll
    for (int j = 0; j < 8; ++j) xf[j] = bf2f((ushort)xv[j]);
    #pragma unroll
    for (int h = 0; h < 8; ++h) {
      const float w = wlds[r][h];
      #pragma unroll
      for (int j = 0; j < 8; ++j) acc[h][j >> 2][j & 3] += w * xf[j];
    }
  }
  #pragma unroll
  for (int h = 0; h < 8; ++h) {
    __syncthreads();
    #pragma unroll
    for (int j = 0; j < 8; ++j) cmb[rg][c8 + j] = acc[h][j >> 2][j & 3];
    __syncthreads();
    const int col = tid * 2;
    float s0 = cmb[0][col] + cmb[1][col] + cmb[2][col] + cmb[3][col];
    float s1 = cmb[0][col + 1] + cmb[1][col + 1] + cmb[2][col + 1] + cmb[3][col + 1];
    *(float2*)(part + (((long)blockIdx.x * 8 + h) << 9) + col) = make_float2(s0, s1);
  }
}

// ======= combine partials + prep1 (gq -> wb/cb), one block per bh ========
__global__ __launch_bounds__(256) void combine_prep1(
    const float* __restrict__ part, const float* __restrict__ WqT,
    const float* __restrict__ bqv, const float* __restrict__ kbv,
    const float* __restrict__ Wk, const float* __restrict__ bkv,
    ushort* __restrict__ wbB, float* __restrict__ cbs)
{
  __shared__ float pxl[512];
  __shared__ float gkb[64];
  const int bh = blockIdx.x, b = bh >> 3, h = bh & 7;
  const int tid = threadIdx.x;
  {
    const int col = tid * 2;
    float s0 = 0.f, s1 = 0.f;
    for (int ch = 0; ch < 64; ++ch) {
      const float* p = part + (((long)((b * 64 + ch) * 8 + h)) << 9) + col;
      s0 += p[0]; s1 += p[1];
    }
    pxl[col] = s0; pxl[col + 1] = s1;
  }
  __syncthreads();
  if (tid < 64) {
    const int d = tid;
    float acc = bqv[h * 64 + d];
    for (int c = 0; c < 512; ++c) acc += pxl[c] * WqT[(long)c * 512 + h * 64 + d];
    gkb[d] = acc * kbv[h * 64 + d];
  }
  __syncthreads();
  if (tid < 64) {
    const int d = tid;
    float s[8] = {};
    for (int dd = 0; dd < 64; ++dd) {
      const float g = gkb[dd];
      const float* wr = Wk + (long)(h * 64 + dd) * 512 + d;
      #pragma unroll
      for (int ki = 0; ki < 8; ++ki) s[ki] += g * wr[ki * 64];
    }
    #pragma unroll
    for (int ki = 0; ki < 8; ++ki)
      wbB[(long)(b * 16 + h) * 512 + d + ki * 64] = f2bf(s[ki]);
    if (d == 0) {
      float t = 0.f;
      for (int dd = 0; dd < 64; ++dd) t += gkb[dd] * bkv[h * 64 + dd];
      cbs[b * 16 + h] = t;
    }
    if (h == 0) {
      #pragma unroll
      for (int hp = 8; hp < 16; ++hp)
        for (int k = d; k < 512; k += 64) wbB[(long)(b * 16 + hp) * 512 + k] = 0;
      if (d < 8) cbs[b * 16 + 8 + d] = 0.f;
    }
  }
}

// ======= combine partials + prep2 (gv), one block per bh =================
__global__ __launch_bounds__(256) void combine_prep2(
    const float* __restrict__ part, const float* __restrict__ WvT,
    const float* __restrict__ bvv, const float* __restrict__ bqv,
    float* __restrict__ gvb)
{
  __shared__ float pxl[512];
  const int bh = blockIdx.x, b = bh >> 3, h = bh & 7;
  const int tid = threadIdx.x;
  {
    const int col = tid * 2;
    float s0 = 0.f, s1 = 0.f;
    for (int ch = 0; ch < 64; ++ch) {
      const float* p = part + (((long)((b * 64 + ch) * 8 + h)) << 9) + col;
      s0 += p[0]; s1 += p[1];
    }
    pxl[col] = s0; pxl[col + 1] = s1;
  }
  __syncthreads();
  if (tid < 64) {
    const int d = tid;
    float acc = bvv[h * 64 + d] + bqv[h * 64 + d];
    for (int c = 0; c < 512; ++c) acc += pxl[c] * WvT[(long)c * 512 + h * 64 + d];
    gvb[b * 512 + h * 64 + d] = acc;
  }
}

// ---------------- BO2[b][n] = bo[n] + gvb[b]·Wo[n,:] ----------------
__global__ __launch_bounds__(256) void bias_gv(
    const float* __restrict__ gv, const float* __restrict__ Wo,
    const float* __restrict__ bo, float* __restrict__ bo2) {
  const int b = blockIdx.x;
  const int n = blockIdx.y * 256 + threadIdx.x;
  const float* g = gv + b * 512;
  const float* w = Wo + (long)n * 512;
  float acc = 0.f;
  for (int d = 0; d < 512; d += 4) {
    float4 wv4 = *(const float4*)(w + d);
    acc += g[d] * wv4.x + g[d + 1] * wv4.y + g[d + 2] * wv4.z + g[d + 3] * wv4.w;
  }
  bo2[b * 512 + n] = bo[n] + acc;
}

// ======== 128x256 tri-buffered bf16 GEMM (Wqo only) =======================
#define MFMA_(d,a,b) d = __builtin_amdgcn_mfma_f32_16x16x32_bf16(a, b, d, 0, 0, 0)

template<int EPI, int LDA, int NN, int KK>
__global__ __launch_bounds__(512, 4) void gemmP(
    const ushort* __restrict__ A, const ushort* __restrict__ W,
    const float* __restrict__ bias, const void* __restrict__ resid,
    const float* __restrict__ mask, void* __restrict__ Out)
{
  constexpr int NBX = NN / 256;
  constexpr int NT = KK / 32;
  __shared__ __align__(16) ushort lds[3][12288];
  const int tid = threadIdx.x;
  const int lane = tid & 63;
  const int w = tid >> 6;
  const int wm = w >> 2, wn = w & 3;

  const int nwg = gridDim.x;
  const int cpx = nwg >> 3;
  const int wg = (blockIdx.x & 7) * cpx + (blockIdx.x >> 3);
  const int bx = wg % NBX, by = wg / NBX;
  const long bm = (long)by * 128;
  const int bn = bx * 256;

  const int scr = tid >> 2, sls = tid & 3;
  const int akU = ((sls ^ (scr & 3) ^ ((scr >> 2) & 3))) * 8;
  const ushort* asrc = A + (bm + scr) * (long)LDA + akU;
  const int rbe = (scr & 31) + ((scr >> 5) << 6);
  const ushort* besrc = W + (long)(bn + rbe) * KK + akU;
  const ushort* bosrc = W + (long)(bn + rbe + 32) * KK + akU;

#define STG(b_, Tt) { \
    gload16(asrc + (Tt) * 32, &lds[b_][tid * 8]); \
    gload16(besrc + (Tt) * 32, &lds[b_][4096 + tid * 8]); \
    gload16(bosrc + (Tt) * 32, &lds[b_][8192 + tid * 8]); }

  STG(0, 0);
  STG(1, 1);

  f4v acc[4][4] = {};

  const int L = lane & 15, q = lane >> 4;
  const int soff = (q ^ (lane & 3) ^ ((lane >> 2) & 3)) * 8;
  const int abase = (wm * 64 + L) * 32 + soff;
  const int bbase = 4096 + (wn * 32 + L) * 32 + soff;

  asm volatile("s_waitcnt vmcnt(3)" ::: "memory");
  asm volatile("s_barrier" ::: "memory");

  for (int T = 0; T < NT; ++T) {
    const ushort* Lp = &lds[T % 3][0];
    bf8v aR[4], bR[4];
    #pragma unroll
    for (int m = 0; m < 4; ++m) aR[m] = *(const bf8v*)(Lp + abase + m * 512);
    bR[0] = *(const bf8v*)(Lp + bbase);
    bR[1] = *(const bf8v*)(Lp + bbase + 512);
    bR[2] = *(const bf8v*)(Lp + bbase + 4096);
    bR[3] = *(const bf8v*)(Lp + bbase + 4096 + 512);
    if (T + 2 < NT) {
      STG((T + 2) % 3, T + 2);
      asm volatile("s_waitcnt vmcnt(3)" ::: "memory");
    } else {
      asm volatile("s_waitcnt vmcnt(0)" ::: "memory");
    }
    asm volatile("s_barrier" ::: "memory");
    __builtin_amdgcn_s_setprio(1);
    #pragma unroll
    for (int m = 0; m < 4; ++m)
      #pragma unroll
      for (int n = 0; n < 4; ++n)
        MFMA_(acc[m][n], aR[m], bR[n]);
    __builtin_amdgcn_s_setprio(0);
  }
#undef STG

  const int colb = bn + wn * 64 + L;
  const long rowb = bm + wm * 64 + q * 4;
  const float* biasp = bias + ((bm >> 13) << 9);
  #pragma unroll
  for (int m = 0; m < 4; ++m) {
    #pragma unroll
    for (int j = 0; j < 4; ++j) {
      const long row = rowb + m * 16 + j;
      #pragma unroll
      for (int n = 0; n < 4; ++n) {
        const int col = colb + n * 16;
        float v = acc[m][n][j] + biasp[col];
        const long idx = row * (long)NN + col;
        ((ushort*)Out)[idx] = f2bf(v + ((const float*)resid)[idx]);
      }
    }
  }
}

// ======== fp8 x fp8 GEMM (non-MX, proven r11): W1 only ====================
// EPI 7: fp8-il out (channel-permuted W1F) = fp8(gelu(acc/8 + b1p))
template<int EPI, int NN, int KK>
__global__ __launch_bounds__(512, 4) void gemmF8(
    const unsigned char* __restrict__ A, const unsigned char* __restrict__ W,
    const float* __restrict__ bias, const void* __restrict__ resid,
    const float* __restrict__ mask, void* __restrict__ Out)
{
  constexpr int NBX = NN / 256;
  constexpr int NT = KK / 64;
  __shared__ __align__(16) unsigned char lds8[3][24576];
  const int tid = threadIdx.x;
  const int lane = tid & 63;
  const int w = tid >> 6;
  const int wm = w >> 2, wn = w & 3;

  const int nwg = gridDim.x;
  const int cpx = nwg >> 3;
  const int wg = (blockIdx.x & 7) * cpx + (blockIdx.x >> 3);
  const int bx = wg % NBX, by = wg / NBX;
  const long bm = (long)by * 128;
  const int bn = bx * 256;

  const int srow = tid >> 2;
  const int sgu = (tid & 3) ^ ((srow >> 1) & 3);
  const unsigned char* asrc = A + (bm + srow) * (long)KK + sgu * 16;
  const unsigned char* b0src = W + (long)(bn + srow) * KK + sgu * 16;
  const unsigned char* b1src = W + (long)(bn + 128 + srow) * KK + sgu * 16;

#define STG8(bf_, Tt) { \
    gload16(asrc + (Tt) * 64, &lds8[bf_][tid * 16]); \
    gload16(b0src + (Tt) * 64, &lds8[bf_][8192 + tid * 16]); \
    gload16(b1src + (Tt) * 64, &lds8[bf_][16384 + tid * 16]); }

  STG8(0, 0);
  STG8(1, 1);

  f4v acc[4][4] = {};

  const int L = lane & 15, q = lane >> 4;
  const int ua = (q ^ ((L >> 1) & 3)) * 16;
  const int arow = (wm * 64 + L) * 64;
  const int brow = 8192 + (wn * 64 + L) * 64;

  asm volatile("s_waitcnt vmcnt(3)" ::: "memory");
  asm volatile("s_barrier" ::: "memory");

  for (int T = 0; T < NT; ++T) {
    const unsigned char* Lp = &lds8[T % 3][0];
    l2v aV[4], bV[4];
    #pragma unroll
    for (int m = 0; m < 4; ++m) aV[m] = *(const l2v*)(Lp + arow + m * 1024 + ua);
    #pragma unroll
    for (int n = 0; n < 4; ++n) bV[n] = *(const l2v*)(Lp + brow + n * 1024 + ua);
    if (T + 2 < NT) {
      STG8((T + 2) % 3, T + 2);
      asm volatile("s_waitcnt vmcnt(3)" ::: "memory");
    } else {
      asm volatile("s_waitcnt vmcnt(0)" ::: "memory");
    }
    asm volatile("s_barrier" ::: "memory");
    __builtin_amdgcn_s_setprio(1);
    #pragma unroll
    for (int m = 0; m < 4; ++m)
      #pragma unroll
      for (int n = 0; n < 4; ++n) {
        acc[m][n] = __builtin_amdgcn_mfma_f32_16x16x32_fp8_fp8(
            aV[m][0], bV[n][0], acc[m][n], 0, 0, 0);
        acc[m][n] = __builtin_amdgcn_mfma_f32_16x16x32_fp8_fp8(
            aV[m][1], bV[n][1], acc[m][n], 0, 0, 0);
      }
    __builtin_amdgcn_s_setprio(0);
  }
#undef STG8

  const long rowb = bm + wm * 64 + q * 4;
  const int gbase = bn + wn * 64;
  if constexpr (EPI == 7) {
    const float4 bp4 = *(const float4*)(bias + gbase + 4 * L);
    #pragma unroll
    for (int m = 0; m < 4; ++m) {
      #pragma unroll
      for (int j = 0; j < 4; ++j) {
        const long row = rowb + m * 16 + j;
        float e0 = gelu_f(acc[m][0][j] * 0.125f + bp4.x);
        float e1 = gelu_f(acc[m][1][j] * 0.125f + bp4.y);
        float e2 = gelu_f(acc[m][2][j] * 0.125f + bp4.z);
        float e3 = gelu_f(acc[m][3][j] * 0.125f + bp4.w);
        unsigned int pw;
#if __has_builtin(__builtin_amdgcn_cvt_pk_fp8_f32)
        int t0 = __builtin_amdgcn_cvt_pk_fp8_f32(e0, e1, 0, false);
        pw = (unsigned int)__builtin_amdgcn_cvt_pk_fp8_f32(e2, e3, t0, true);
#else
        pw = (unsigned int)f2fp8(e0) | ((unsigned int)f2fp8(e1) << 8)
           | ((unsigned int)f2fp8(e2) << 16) | ((unsigned int)f2fp8(e3) << 24);
#endif
        *(unsigned int*)((unsigned char*)Out + row * (long)NN + gbase + 4 * L) = pw;
      }
    }
  } else {
    #pragma unroll
    for (int m = 0; m < 4; ++m) {
      #pragma unroll
      for (int j = 0; j < 4; ++j) {
        const long row = rowb + m * 16 + j;
        const float mk = mask[row];
        #pragma unroll
        for (int n = 0; n < 4; ++n) {
          const int col = gbase + n * 16 + L;
          float v = acc[m][n][j] * 0.125f + bias[col];
          const long idx = row * (long)NN + col;
          ((float*)Out)[idx] =
              (bf2f(((const ushort*)resid)[idx]) + gelu_f(v)) * mk;
        }
      }
    }
  }
}

// ======== W2 MX GEMM: 128x128 tile, K=128 mfma_scale, reg-budgeted ========
// acc[4][2](32) + aOp[4](32) + bOp[2](16) ~= 105 VGPR <= 128 -> no spill.
// Tri-buffered (48KB), 2 gload16/thread/tile, counted vmcnt(2).
// out f32 = (bf2f(resid) + gelu(acc/8 + bias))*mask
__global__ __launch_bounds__(512, 4) void gemmF8MX2(
    const unsigned char* __restrict__ A, const unsigned char* __restrict__ W,
    const float* __restrict__ bias, const ushort* __restrict__ resid,
    const float* __restrict__ mask, float* __restrict__ Out)
{
  constexpr int NN = 512, KK = 2048;
  constexpr int NBX = 4;
  constexpr int NT = KK / 64;        // 32 tiles, 16 pairs
  __shared__ __align__(16) unsigned char lds8[3][16384];
  const int tid = threadIdx.x;
  const int lane = tid & 63;
  const int w = tid >> 6;
  const int wm = w >> 2, wn = w & 3;   // 2M x 4N waves; per-wave 64x32

  const int nwg = gridDim.x;
  const int cpx = nwg >> 3;
  const int wg = (blockIdx.x & 7) * cpx + (blockIdx.x >> 3);
  const int bx = wg % NBX, by = wg / NBX;
  const long bm = (long)by * 128;
  const int bn = bx * 128;

  const int srow = tid >> 2;
  const int sgu = (tid & 3) ^ ((srow >> 1) & 3);
  const unsigned char* asrc = A + (bm + srow) * (long)KK + sgu * 16;
  const unsigned char* bsrc = W + (long)(bn + srow) * KK + sgu * 16;

#define STGX(bf_, Tt) { \
    gload16(asrc + (Tt) * 64, &lds8[bf_][tid * 16]); \
    gload16(bsrc + (Tt) * 64, &lds8[bf_][8192 + tid * 16]); }

  STGX(0, 0);
  STGX(1, 1);

  f4v acc[4][2] = {};
  const int L = lane & 15, q = lane >> 4;
  const int ua = (q ^ ((L >> 1) & 3)) * 16;
  const int arow = (wm * 64 + L) * 64;           // + m*1024
  const int brow = 8192 + (wn * 32 + L) * 64;    // + n*1024

  asm volatile("s_waitcnt vmcnt(2)" ::: "memory");
  asm volatile("s_barrier" ::: "memory");

  l4v aOp[4], bOp[2];
  for (int T2 = 0; T2 < NT / 2; ++T2) {
    {
      const int T = 2 * T2;
      const unsigned char* Lp = &lds8[T % 3][0];
      #pragma unroll
      for (int m = 0; m < 4; ++m) {
        l2v r = *(const l2v*)(Lp + arow + m * 1024 + ua);
        aOp[m][0] = r[0]; aOp[m][1] = r[1];
      }
      #pragma unroll
      for (int n = 0; n < 2; ++n) {
        l2v r = *(const l2v*)(Lp + brow + n * 1024 + ua);
        bOp[n][0] = r[0]; bOp[n][1] = r[1];
      }
      if (T + 2 < NT) {
        STGX((T + 2) % 3, T + 2);
        asm volatile("s_waitcnt vmcnt(2)" ::: "memory");
      } else {
        asm volatile("s_waitcnt vmcnt(0)" ::: "memory");
      }
      asm volatile("s_barrier" ::: "memory");
    }
    {
      const int T = 2 * T2 + 1;
      const unsigned char* Lp = &lds8[T % 3][0];
      #pragma unroll
      for (int m = 0; m < 4; ++m) {
        l2v r = *(const l2v*)(Lp + arow + m * 1024 + ua);
        aOp[m][2] = r[0]; aOp[m][3] = r[1];
      }
      #pragma unroll
      for (int n = 0; n < 2; ++n) {
        l2v r = *(const l2v*)(Lp + brow + n * 1024 + ua);
        bOp[n][2] = r[0]; bOp[n][3] = r[1];
      }
      if (T + 2 < NT) {
        STGX((T + 2) % 3, T + 2);
        asm volatile("s_waitcnt vmcnt(2)" ::: "memory");
      } else {
        asm volatile("s_waitcnt vmcnt(0)" ::: "memory");
      }
      asm volatile("s_barrier" ::: "memory");
      __builtin_amdgcn_s_setprio(1);
      #pragma unroll
      for (int m = 0; m < 4; ++m) {
        const i8x am = __builtin_bit_cast(i8x, aOp[m]);
        #pragma unroll
        for (int n = 0; n < 2; ++n) {
          acc[m][n] = __builtin_amdgcn_mfma_scale_f32_16x16x128_f8f6f4(
              am, __builtin_bit_cast(i8x, bOp[n]), acc[m][n],
              0, 0, 0, 0x7F7F7F7F, 0, 0x7F7F7F7F);
        }
      }
      __builtin_amdgcn_s_setprio(0);
    }
  }
#undef STGX

  const long rowb = bm + wm * 64 + q * 4;
  const int gbase = bn + wn * 32;
  #pragma unroll
  for (int m = 0; m < 4; ++m) {
    #pragma unroll
    for (int j = 0; j < 4; ++j) {
      const long row = rowb + m * 16 + j;
      const float mk = mask[row];
      #pragma unroll
      for (int n = 0; n < 2; ++n) {
        const int col = gbase + n * 16 + L;
        float v = acc[m][n][j] * 0.125f + bias[col];
        const long idx = row * (long)NN + col;
        Out[idx] = (bf2f(resid[idx]) + gelu_f(v)) * mk;
      }
    }
  }
}

// ---------------- host ----------------
extern "C" void kernel_launch(void* const* d_in, const int* in_sizes, int n_in,
                              void* d_out, int out_size, void* d_ws, size_t ws_size,
                              hipStream_t stream) {
  const float* x    = (const float*)d_in[0];
  const float* mask = (const float*)d_in[1];
  const float* Wq   = (const float*)d_in[2];
  const float* bq   = (const float*)d_in[3];
  const float* Wk   = (const float*)d_in[4];
  const float* bk   = (const float*)d_in[5];
  const float* Wv   = (const float*)d_in[6];
  const float* bv   = (const float*)d_in[7];
  const float* qa   = (const float*)d_in[8];
  const float* kb   = (const float*)d_in[9];
  const float* Wo   = (const float*)d_in[10];
  const float* bo   = (const float*)d_in[11];
  const float* g0   = (const float*)d_in[12];
  const float* be0  = (const float*)d_in[13];
  const float* g1   = (const float*)d_in[14];
  const float* be1  = (const float*)d_in[15];
  const float* W1   = (const float*)d_in[16];
  const float* b1   = (const float*)d_in[17];
  const float* W2   = (const float*)d_in[18];
  const float* b2   = (const float*)d_in[19];
  float* out = (float*)d_out;

  const int M = 65536;          // B*N
  char* ws = (char*)d_ws;
  const size_t MB = 1024 * 1024;
  ushort* XN  = (ushort*)(ws);                           // [0,64) bf16 ln0 out
  ushort* X1  = (ushort*)(ws + 64 * MB);                 // [64,128) bf16
  unsigned char* XN1F = (unsigned char*)(ws + 128 * MB); // [128,160) fp8 il
  unsigned char* H1F  = (unsigned char*)(ws + 192 * MB); // [192,320) fp8 il
  float*  AL  = (float*)(ws + 320 * MB);                 // 2MB
  float*  BL  = (float*)(ws + 322 * MB);                 // 2MB
  float*  PART= (float*)(ws + 324 * MB);                 // 8MB
  char* base = ws + 448 * MB;
  unsigned char* W1F = (unsigned char*)(base);           // 1MB
  unsigned char* W2F = (unsigned char*)(base + 2 * MB);  // 1MB
  ushort* WqoB = (ushort*)(base + 4 * MB);
  float*  WqT  = (float*)(base + 4 * MB + 512 * 1024);
  float*  WvT  = (float*)(base + 5 * MB + 512 * 1024);
  ushort* waB  = (ushort*)(base + 6 * MB + 512 * 1024);
  ushort* wbB  = (ushort*)(base + 6 * MB + 528 * 1024);
  float*  ca   = (float*)(base + 6 * MB + 656 * 1024);
  float*  cbs  = (float*)(base + 6 * MB + 660 * 1024);
  float*  GVB  = (float*)(base + 6 * MB + 920 * 1024);
  float*  BO2  = (float*)(base + 6 * MB + 936 * 1024);
  float*  B1P  = (float*)(base + 6 * MB + 952 * 1024);   // 8KB

  // ---- weight precompute ----
  cvt_w1_fp8il<<<1024, 256, 0, stream>>>(W1, W1F);
  perm_b1<<<8, 256, 0, stream>>>(b1, B1P);
  cvt_f32_fp8il<<<1024, 256, 0, stream>>>(W2, W2F, 1048576, 2047);
  wqo_kernel<<<64, 256, 0, stream>>>(Wo, Wq, WqoB);
  wa_kernel<<<16, 256, 0, stream>>>(qa, Wq, bq, waB, ca);
  transpose512<<<256, 256, 0, stream>>>(Wq, WqT);
  transpose512<<<256, 256, 0, stream>>>(Wv, WvT);

  // ---- fused LN0 (+mask) + alpha logits ----
  ln0_alpha<<<M / 16, 256, 0, stream>>>(x, g0, be0, mask, waB, ca, XN, AL);

  // ---- stage 1: softmax -> pooled x -> gq/wb ----
  softmax_rows<<<64, 1024, 0, stream>>>(AL);
  pool_w<<<512, 256, 0, stream>>>(XN, AL, PART);
  combine_prep1<<<64, 256, 0, stream>>>(PART, WqT, bq, kb, Wk, bk, wbB, cbs);

  // ---- stage 2: beta logits -> softmax -> pooled x -> gv ----
  logits_k<8192, 16><<<1024, 256, 0, stream>>>(XN, wbB, cbs, mask, BL);
  softmax_rows<<<64, 1024, 0, stream>>>(BL);
  pool_w<<<512, 256, 0, stream>>>(XN, BL, PART);
  combine_prep2<<<64, 256, 0, stream>>>(PART, WvT, bv, bq, GVB);
  bias_gv<<<dim3(8, 2), 256, 0, stream>>>(GVB, Wo, bo, BO2);

  // ---- attention out: X1(bf16) = xn @ Wqo^T + BO2[b] + x ----
  gemmP<5, 512, 512, 512><<<2 * (M / 128), 512, 0, stream>>>(
      XN, WqoB, BO2, x, nullptr, X1);

  // ---- LN1 -> XN1F (fp8, k-interleaved) ----
  ln_rows_fp8il<<<M / 4, 256, 0, stream>>>(X1, g1, be1, XN1F);

  // ---- MLP: W1 (non-MX, proven) -> H1F; W2 (MX K=128) -> out ----
  gemmF8<7, 2048, 512><<<8 * (M / 128), 512, 0, stream>>>(
      XN1F, W1F, B1P, nullptr, nullptr, H1F);
  gemmF8MX2<<<4 * (M / 128), 512, 0, stream>>>(
      H1F, W2F, b2, X1, mask, out);
}

// Round 14
// 574.821 us; speedup vs baseline: 1.6550x; 1.0042x over previous
//
#include <hip/hip_runtime.h>
#include <hip/hip_bf16.h>
#include <hip/hip_fp8.h>
#include <math.h>

typedef short s8v __attribute__((ext_vector_type(8)));
typedef short s4v __attribute__((ext_vector_type(4)));
typedef __bf16 bf8v __attribute__((ext_vector_type(8)));
typedef float f4v __attribute__((ext_vector_type(4)));
typedef long l2v __attribute__((ext_vector_type(2)));
typedef long l4v __attribute__((ext_vector_type(4)));
typedef int i8x __attribute__((ext_vector_type(8)));

#define GLOBAL_AS __attribute__((address_space(1)))
#define LDS_AS __attribute__((address_space(3)))

static __device__ __forceinline__ float bf2f(ushort u) {
  return __builtin_bit_cast(float, (unsigned int)u << 16);
}
static __device__ __forceinline__ ushort f2bf(float f) {
  unsigned int u = __builtin_bit_cast(unsigned int, f);
  u += 0x7FFFu + ((u >> 16) & 1u);
  return (ushort)(u >> 16);
}
static __device__ __forceinline__ unsigned char f2fp8(float f) {
#if __has_builtin(__builtin_amdgcn_cvt_pk_fp8_f32)
  int p = __builtin_amdgcn_cvt_pk_fp8_f32(f, f, 0, false);
  return (unsigned char)(p & 0xFF);
#else
  __hip_fp8_e4m3 v(f);
  return (unsigned char)v.__x;
#endif
}
// fast tanh-gelu with hardware rcp
static __device__ __forceinline__ float gelu_f(float v) {
  float t = v * v;
  float u = v * (0.0356774081f * t + 0.7978845608f);
  float e = __expf(-2.0f * u);
  return v * __builtin_amdgcn_rcpf(1.0f + e);
}
static __device__ __forceinline__ float wave_max_f(float v) {
  #pragma unroll
  for (int o = 32; o >= 1; o >>= 1) v = fmaxf(v, __shfl_xor(v, o));
  return v;
}
static __device__ __forceinline__ float wave_sum_f(float v) {
  #pragma unroll
  for (int o = 32; o >= 1; o >>= 1) v += __shfl_xor(v, o);
  return v;
}
static __device__ __forceinline__ void gload16(const void* g, const void* l) {
  __builtin_amdgcn_global_load_lds(
      (const GLOBAL_AS unsigned int*)g,
      (LDS_AS unsigned int*)l, 16, 0, 0);
}

// ---- weight fp32 -> fp8 e4m3, scaled x8, k-interleaved within 64-groups ----
__global__ void cvt_f32_fp8il(const float* __restrict__ in,
                              unsigned char* __restrict__ out, int n, int kmask) {
  int i = (blockIdx.x * 256 + threadIdx.x) * 4;
  if (i >= n) return;
  float4 v = *(const float4*)(in + i);
  const int k = i & kmask;
  const int r = k & 63;
  const int qq = (r >> 3) & 3, h = (r >> 5) & 1, j = r & 7;
  const long o = (long)(i - r) + qq * 16 + h * 8 + j;
  uchar4 ob;
  ob.x = f2fp8(v.x * 8.f); ob.y = f2fp8(v.y * 8.f);
  ob.z = f2fp8(v.z * 8.f); ob.w = f2fp8(v.w * 8.f);
  *(uchar4*)(out + o) = ob;
}

// ---- W1 -> fp8 with OUTPUT-ROW permutation (contiguous epilogue writes) ----
__global__ void cvt_w1_fp8il(const float* __restrict__ in,
                             unsigned char* __restrict__ out) {
  int i = (blockIdx.x * 256 + threadIdx.x) * 4;   // over 2048*512
  const int ro = i >> 9;
  const int k4 = i & 511;
  const int g = ro >> 6, fr = ro & 63;
  const int L = fr & 15, nn = fr >> 4;
  const int sr = g * 64 + ((L >> 1) & 1) * 32 + (L >> 2) * 8 + (L & 1) * 4 + nn;
  float4 v = *(const float4*)(in + (long)sr * 512 + k4);
  const int r = k4 & 63;
  const int o = (k4 - r) + ((r >> 3) & 3) * 16 + (r >> 5) * 8 + (r & 7);
  uchar4 ob;
  ob.x = f2fp8(v.x * 8.f); ob.y = f2fp8(v.y * 8.f);
  ob.z = f2fp8(v.z * 8.f); ob.w = f2fp8(v.w * 8.f);
  *(uchar4*)(out + (long)ro * 512 + o) = ob;
}

// ---- permuted bias: b1p[g*64+p] = b1[g*64+kc(p)] ----
__global__ void perm_b1(const float* __restrict__ b1, float* __restrict__ b1p) {
  const int p = blockIdx.x * 256 + threadIdx.x;   // 2048
  const int g = p >> 6, r = p & 63;
  const int kc = ((r >> 3) & 1) * 32 + (r >> 4) * 8 + ((r >> 2) & 1) * 4 + (r & 3);
  b1p[p] = b1[g * 64 + kc];
}

// ---------------- 512x512 f32 transpose ----------------
__global__ __launch_bounds__(256) void transpose512(
    const float* __restrict__ in, float* __restrict__ out) {
  __shared__ float t[32][33];
  const int bx = blockIdx.x & 15, by = blockIdx.x >> 4;
  const int tx = threadIdx.x & 31, ty = threadIdx.x >> 5;
  #pragma unroll
  for (int i = 0; i < 4; ++i)
    t[ty + i * 8][tx] = in[(long)(by * 32 + ty + i * 8) * 512 + bx * 32 + tx];
  __syncthreads();
  #pragma unroll
  for (int i = 0; i < 4; ++i)
    out[(long)(bx * 32 + ty + i * 8) * 512 + by * 32 + tx] = t[tx][ty + i * 8];
}

// ---------------- Wqo = Wo @ Wq  (f32 inputs, bf16 out) ----------------
__global__ __launch_bounds__(256) void wqo_kernel(
    const float* __restrict__ Wo, const float* __restrict__ Wq,
    ushort* __restrict__ WqoB)
{
  __shared__ float lO[64][33];
  __shared__ float lQ[32][65];
  const int t = threadIdx.x;
  const int bi = (blockIdx.x & 7) * 64, bj = (blockIdx.x >> 3) * 64;
  float acc[16] = {};
  for (int k0 = 0; k0 < 512; k0 += 32) {
    __syncthreads();
    {
      const int r = t >> 2, c = (t & 3) * 8;
      #pragma unroll
      for (int j = 0; j < 8; ++j) lO[r][c + j] = Wo[(long)(bi + r) * 512 + k0 + c + j];
      const int r2 = t >> 3, c2 = (t & 7) * 8;
      #pragma unroll
      for (int j = 0; j < 8; ++j) lQ[r2][c2 + j] = Wq[(long)(k0 + r2) * 512 + bj + c2 + j];
    }
    __syncthreads();
    const int j = t & 63, ig = t >> 6;
    for (int kk = 0; kk < 32; ++kk) {
      float q = lQ[kk][j];
      #pragma unroll
      for (int ii = 0; ii < 16; ++ii) acc[ii] += lO[ig * 16 + ii][kk] * q;
    }
  }
  const int j = t & 63, ig = t >> 6;
  #pragma unroll
  for (int ii = 0; ii < 16; ++ii)
    WqoB[(long)(bi + ig * 16 + ii) * 512 + bj + j] = f2bf(acc[ii]);
}

// ---------------- wa[h,k] = sum_d qa[h,d] Wq[h*64+d,k]; ca[h] = qa_h . bq_h
__global__ __launch_bounds__(256) void wa_kernel(
    const float* __restrict__ qa, const float* __restrict__ Wq,
    const float* __restrict__ bqv, ushort* __restrict__ waB, float* __restrict__ ca)
{
  __shared__ float ql[64];
  const int h = blockIdx.x;   // 0..15 (8..15 pad)
  const int t = threadIdx.x;
  if (h >= 8) {
    waB[h * 512 + t] = 0; waB[h * 512 + 256 + t] = 0;
    if (t == 0) ca[h] = 0.f;
    return;
  }
  if (t < 64) ql[t] = qa[h * 64 + t];
  __syncthreads();
  #pragma unroll
  for (int half = 0; half < 2; ++half) {
    const int k = half * 256 + t;
    float s = 0;
    for (int dd = 0; dd < 64; ++dd) s += ql[dd] * Wq[(long)(h * 64 + dd) * 512 + k];
    waB[h * 512 + k] = f2bf(s);
  }
  if (t == 0) {
    float s = 0;
    for (int dd = 0; dd < 64; ++dd) s += ql[dd] * bqv[h * 64 + dd];
    ca[h] = s;
  }
}

// ======= fused LN0 + alpha logits ========================================
__global__ __launch_bounds__(256) void ln0_alpha(
    const float* __restrict__ x, const float* __restrict__ gam,
    const float* __restrict__ bet, const float* __restrict__ mask,
    const ushort* __restrict__ waB, const float* __restrict__ ca,
    ushort* __restrict__ out, float* __restrict__ AL)
{
  __shared__ ushort wal[8 * 512];
  const int tid = threadIdx.x, lane = tid & 63, wv = tid >> 6;
  *(s8v*)(wal + tid * 8) = *(const s8v*)(waB + tid * 8);
  *(s8v*)(wal + 2048 + tid * 8) = *(const s8v*)(waB + 2048 + tid * 8);
  const float* gp = gam + lane * 8;
  const float* bp = bet + lane * 8;
  float4 g0 = *(const float4*)gp, g1 = *(const float4*)(gp + 4);
  float4 c0 = *(const float4*)bp, c1 = *(const float4*)(bp + 4);
  const float gg[8] = {g0.x, g0.y, g0.z, g0.w, g1.x, g1.y, g1.z, g1.w};
  const float cc[8] = {c0.x, c0.y, c0.z, c0.w, c1.x, c1.y, c1.z, c1.w};
  __syncthreads();
  const long row0 = (long)blockIdx.x * 16 + wv * 4;
  for (int rr = 0; rr < 4; ++rr) {
    const long row = row0 + rr;
    const float* xp = x + row * 512 + lane * 8;
    float4 a = *(const float4*)xp;
    float4 b = *(const float4*)(xp + 4);
    float s = a.x + a.y + a.z + a.w + b.x + b.y + b.z + b.w;
    float q = a.x*a.x + a.y*a.y + a.z*a.z + a.w*a.w
            + b.x*b.x + b.y*b.y + b.z*b.z + b.w*b.w;
    s = wave_sum_f(s); q = wave_sum_f(q);
    const float m = s * (1.f / 512.f);
    const float var = q * (1.f / 512.f) - m * m;
    const float r = rsqrtf(var + 1e-5f);
    const float mk = mask[row];
    const float xin[8] = {a.x, a.y, a.z, a.w, b.x, b.y, b.z, b.w};
    float of[8];
    s8v o;
    #pragma unroll
    for (int j = 0; j < 8; ++j) {
      of[j] = ((xin[j] - m) * r * gg[j] + cc[j]) * mk;
      o[j] = (short)f2bf(of[j]);
    }
    *(s8v*)(out + row * 512 + lane * 8) = o;
    float dh[8];
    #pragma unroll
    for (int h = 0; h < 8; ++h) {
      s8v wa8 = *(const s8v*)(wal + h * 512 + lane * 8);
      float d = 0.f;
      #pragma unroll
      for (int j = 0; j < 8; ++j) d += of[j] * bf2f((ushort)wa8[j]);
      dh[h] = wave_sum_f(d);
    }
    if (lane == 0) {
      const int bb = (int)(row >> 13);
      const int n = (int)(row & 8191);
      #pragma unroll
      for (int h = 0; h < 8; ++h) {
        float lg = (dh[h] + ca[h]) * 0.125f;
        if (mk == 0.f) lg = -1e30f;
        AL[((long)((bb << 3) + h) << 13) + n] = lg;
      }
    }
  }
}

// ---- LayerNorm (bf16 in) -> fp8 e4m3 out, k-interleaved layout ----------
__global__ __launch_bounds__(256) void ln_rows_fp8il(
    const ushort* __restrict__ x, const float* __restrict__ gam,
    const float* __restrict__ bet, unsigned char* __restrict__ out)
{
  const int tid = threadIdx.x, lane = tid & 63, wv = tid >> 6;
  const long row = (long)blockIdx.x * 4 + wv;
  s8v v = *(const s8v*)(x + row * 512 + lane * 8);
  float xv[8];
  #pragma unroll
  for (int j = 0; j < 8; ++j) xv[j] = bf2f((ushort)v[j]);
  float s = 0.f, q = 0.f;
  #pragma unroll
  for (int j = 0; j < 8; ++j) { s += xv[j]; q += xv[j] * xv[j]; }
  s = wave_sum_f(s); q = wave_sum_f(q);
  float m = s * (1.f / 512.f);
  float var = q * (1.f / 512.f) - m * m;
  float r = rsqrtf(var + 1e-5f);
  const float* gp = gam + lane * 8;
  const float* bp = bet + lane * 8;
  float4 g0 = *(const float4*)gp, g1 = *(const float4*)(gp + 4);
  float4 c0 = *(const float4*)bp, c1 = *(const float4*)(bp + 4);
  float gg[8] = {g0.x, g0.y, g0.z, g0.w, g1.x, g1.y, g1.z, g1.w};
  float cc[8] = {c0.x, c0.y, c0.z, c0.w, c1.x, c1.y, c1.z, c1.w};
  unsigned long long pk = 0;
  #pragma unroll
  for (int j = 0; j < 8; ++j) {
    unsigned char b8 = f2fp8((xv[j] - m) * r * gg[j] + cc[j]);
    pk |= (unsigned long long)b8 << (8 * j);
  }
  *(unsigned long long*)(out + row * 512 + (lane >> 3) * 64
                         + (lane & 3) * 16 + ((lane >> 2) & 1) * 8) = pk;
}

// ======= beta logits via MFMA, LDS-staged coalesced XN reads =============
template<int BS, int CS>
__global__ __launch_bounds__(256) void logits_k(
    const ushort* __restrict__ XN, const ushort* __restrict__ Wl,
    const float* __restrict__ cvec, const float* __restrict__ mask,
    float* __restrict__ outL)
{
  __shared__ ushort lw[16 * 512];
  __shared__ __align__(16) ushort lx[64 * 512];
  const int tid = threadIdx.x, lane = tid & 63, wv = tid >> 6;
  const long r0 = (long)blockIdx.x * 64;
  const int b = (int)(r0 >> 13);
  #pragma unroll
  for (int i = 0; i < 16; ++i) {
    const int U = i * 256 + tid;
    const int r = U >> 6, u1 = U & 63;
    const int us = u1 ^ (r & 7);
    gload16(XN + (r0 + r) * 512 + us * 8, lx + (long)U * 8);
  }
  #pragma unroll
  for (int i = 0; i < 4; ++i) {
    const int u = tid + i * 256;
    const int h2 = u >> 6, uu = u & 63;
    s8v v = *(const s8v*)(Wl + (long)b * BS + h2 * 512 + uu * 8);
    *(s8v*)(lw + h2 * 512 + (uu ^ (h2 & 7)) * 8) = v;
  }
  __syncthreads();
  const int h = lane & 15, q = lane >> 4;
  const int rloc = wv * 16 + (lane & 15);
  const ushort* axp = lx + rloc * 512;
  f4v acc = {};
  #pragma unroll
  for (int t = 0; t < 16; ++t) {
    bf8v a = *(const bf8v*)(axp + (((t * 4 + q) ^ (rloc & 7))) * 8);
    bf8v bb = *(const bf8v*)(lw + h * 512 + (((t * 4 + q) ^ (h & 7))) * 8);
    acc = __builtin_amdgcn_mfma_f32_16x16x32_bf16(a, bb, acc, 0, 0, 0);
  }
  const float cv = cvec[b * CS + h];
  const long rw = r0 + wv * 16;
  #pragma unroll
  for (int j = 0; j < 4; ++j) {
    const long n = rw + q * 4 + j;
    float v = (acc[j] + cv) * 0.125f;
    if (mask[n] == 0.f) v = -1e30f;
    if (h < 8) outL[((long)((b << 3) + h) << 13) + (n & 8191)] = v;
  }
}

// ---------------- softmax over N=8192 per (b,h), in place ----------------
__global__ __launch_bounds__(1024) void softmax_rows(float* __restrict__ L)
{
  __shared__ float red[16];
  __shared__ float bc;
  const int tid = threadIdx.x, lane = tid & 63, wv = tid >> 6;
  float* p = L + ((long)blockIdx.x << 13) + tid * 8;
  float4 v0 = *(float4*)p;
  float4 v1 = *(float4*)(p + 4);
  float m = fmaxf(fmaxf(fmaxf(v0.x, v0.y), fmaxf(v0.z, v0.w)),
                  fmaxf(fmaxf(v1.x, v1.y), fmaxf(v1.z, v1.w)));
  m = wave_max_f(m);
  if (lane == 0) red[wv] = m;
  __syncthreads();
  if (tid < 64) {
    float t = (lane < 16) ? red[lane] : -INFINITY;
    t = wave_max_f(t);
    if (lane == 0) bc = t;
  }
  __syncthreads();
  const float gm = bc;
  v0.x = __expf(v0.x - gm); v0.y = __expf(v0.y - gm);
  v0.z = __expf(v0.z - gm); v0.w = __expf(v0.w - gm);
  v1.x = __expf(v1.x - gm); v1.y = __expf(v1.y - gm);
  v1.z = __expf(v1.z - gm); v1.w = __expf(v1.w - gm);
  float s = v0.x + v0.y + v0.z + v0.w + v1.x + v1.y + v1.z + v1.w;
  s = wave_sum_f(s);
  __syncthreads();
  if (lane == 0) red[wv] = s;
  __syncthreads();
  if (tid < 64) {
    float t = (lane < 16) ? red[lane] : 0.f;
    t = wave_sum_f(t);
    if (lane == 0) bc = t;
  }
  __syncthreads();
  const float inv = 1.0f / bc;
  v0.x *= inv; v0.y *= inv; v0.z *= inv; v0.w *= inv;
  v1.x *= inv; v1.y *= inv; v1.z *= inv; v1.w *= inv;
  *(float4*)p = v0;
  *(float4*)(p + 4) = v1;
}

// ---------------- weighted pool partials ----------------
__global__ __launch_bounds__(256) void pool_w(
    const ushort* __restrict__ XN, const float* __restrict__ wbuf,
    float* __restrict__ part)
{
  __shared__ float wlds[128][8];
  __shared__ float cmb[4][512];
  const int tid = threadIdx.x;
  const int b = blockIdx.x >> 6, ch = blockIdx.x & 63;
  const long g0 = ((long)b << 13) + ch * 128;
  if (tid < 128) {
    #pragma unroll
    for (int h = 0; h < 8; ++h)
      wlds[tid][h] = wbuf[(((long)(b * 8 + h)) << 13) + ch * 128 + tid];
  }
  __syncthreads();
  const int rg = tid >> 6, c8 = (tid & 63) * 8;
  f4v acc[8][2] = {};
  for (int it = 0; it < 32; ++it) {
    const int r = it * 4 + rg;
    s8v xv = *(const s8v*)(XN + (g0 + r) * 512 + c8);
    float xf[8];
    #pragma unroll
    for (int j = 0; j < 8; ++j) xf[j] = bf2f((ushort)xv[j]);
    #pragma unroll
    for (int h = 0; h < 8; ++h) {
      const float w = wlds[r][h];
      #pragma unroll
      for (int j = 0; j < 8; ++j) acc[h][j >> 2][j & 3] += w * xf[j];
    }
  }
  #pragma unroll
  for (int h = 0; h < 8; ++h) {
    __syncthreads();
    #pragma unroll
    for (int j = 0; j < 8; ++j) cmb[rg][c8 + j] = acc[h][j >> 2][j & 3];
    __syncthreads();
    const int col = tid * 2;
    float s0 = cmb[0][col] + cmb[1][col] + cmb[2][col] + cmb[3][col];
    float s1 = cmb[0][col + 1] + cmb[1][col + 1] + cmb[2][col + 1] + cmb[3][col + 1];
    *(float2*)(part + (((long)blockIdx.x * 8 + h) << 9) + col) = make_float2(s0, s1);
  }
}

// ======= combine partials + prep1 (gq -> wb/cb), one block per bh ========
__global__ __launch_bounds__(256) void combine_prep1(
    const float* __restrict__ part, const float* __restrict__ WqT,
    const float* __restrict__ bqv, const float* __restrict__ kbv,
    const float* __restrict__ Wk, const float* __restrict__ bkv,
    ushort* __restrict__ wbB, float* __restrict__ cbs)
{
  __shared__ float pxl[512];
  __shared__ float gkb[64];
  const int bh = blockIdx.x, b = bh >> 3, h = bh & 7;
  const int tid = threadIdx.x;
  {
    const int col = tid * 2;
    float s0 = 0.f, s1 = 0.f;
    for (int ch = 0; ch < 64; ++ch) {
      const float* p = part + (((long)((b * 64 + ch) * 8 + h)) << 9) + col;
      s0 += p[0]; s1 += p[1];
    }
    pxl[col] = s0; pxl[col + 1] = s1;
  }
  __syncthreads();
  if (tid < 64) {
    const int d = tid;
    float acc = bqv[h * 64 + d];
    for (int c = 0; c < 512; ++c) acc += pxl[c] * WqT[(long)c * 512 + h * 64 + d];
    gkb[d] = acc * kbv[h * 64 + d];
  }
  __syncthreads();
  if (tid < 64) {
    const int d = tid;
    float s[8] = {};
    for (int dd = 0; dd < 64; ++dd) {
      const float g = gkb[dd];
      const float* wr = Wk + (long)(h * 64 + dd) * 512 + d;
      #pragma unroll
      for (int ki = 0; ki < 8; ++ki) s[ki] += g * wr[ki * 64];
    }
    #pragma unroll
    for (int ki = 0; ki < 8; ++ki)
      wbB[(long)(b * 16 + h) * 512 + d + ki * 64] = f2bf(s[ki]);
    if (d == 0) {
      float t = 0.f;
      for (int dd = 0; dd < 64; ++dd) t += gkb[dd] * bkv[h * 64 + dd];
      cbs[b * 16 + h] = t;
    }
    if (h == 0) {
      #pragma unroll
      for (int hp = 8; hp < 16; ++hp)
        for (int k = d; k < 512; k += 64) wbB[(long)(b * 16 + hp) * 512 + k] = 0;
      if (d < 8) cbs[b * 16 + 8 + d] = 0.f;
    }
  }
}

// ======= combine partials + prep2 (gv), one block per bh =================
__global__ __launch_bounds__(256) void combine_prep2(
    const float* __restrict__ part, const float* __restrict__ WvT,
    const float* __restrict__ bvv, const float* __restrict__ bqv,
    float* __restrict__ gvb)
{
  __shared__ float pxl[512];
  const int bh = blockIdx.x, b = bh >> 3, h = bh & 7;
  const int tid = threadIdx.x;
  {
    const int col = tid * 2;
    float s0 = 0.f, s1 = 0.f;
    for (int ch = 0; ch < 64; ++ch) {
      const float* p = part + (((long)((b * 64 + ch) * 8 + h)) << 9) + col;
      s0 += p[0]; s1 += p[1];
    }
    pxl[col] = s0; pxl[col + 1] = s1;
  }
  __syncthreads();
  if (tid < 64) {
    const int d = tid;
    float acc = bvv[h * 64 + d] + bqv[h * 64 + d];
    for (int c = 0; c < 512; ++c) acc += pxl[c] * WvT[(long)c * 512 + h * 64 + d];
    gvb[b * 512 + h * 64 + d] = acc;
  }
}

// ---------------- BO2[b][n] = bo[n] + gvb[b]·Wo[n,:] ----------------
__global__ __launch_bounds__(256) void bias_gv(
    const float* __restrict__ gv, const float* __restrict__ Wo,
    const float* __restrict__ bo, float* __restrict__ bo2) {
  const int b = blockIdx.x;
  const int n = blockIdx.y * 256 + threadIdx.x;
  const float* g = gv + b * 512;
  const float* w = Wo + (long)n * 512;
  float acc = 0.f;
  for (int d = 0; d < 512; d += 4) {
    float4 wv4 = *(const float4*)(w + d);
    acc += g[d] * wv4.x + g[d + 1] * wv4.y + g[d + 2] * wv4.z + g[d + 3] * wv4.w;
  }
  bo2[b * 512 + n] = bo[n] + acc;
}

// ======== 128x256 tri-buffered bf16 GEMM (Wqo only) =======================
#define MFMA_(d,a,b) d = __builtin_amdgcn_mfma_f32_16x16x32_bf16(a, b, d, 0, 0, 0)

template<int EPI, int LDA, int NN, int KK>
__global__ __launch_bounds__(512, 4) void gemmP(
    const ushort* __restrict__ A, const ushort* __restrict__ W,
    const float* __restrict__ bias, const void* __restrict__ resid,
    const float* __restrict__ mask, void* __restrict__ Out)
{
  constexpr int NBX = NN / 256;
  constexpr int NT = KK / 32;
  __shared__ __align__(16) ushort lds[3][12288];
  const int tid = threadIdx.x;
  const int lane = tid & 63;
  const int w = tid >> 6;
  const int wm = w >> 2, wn = w & 3;

  const int nwg = gridDim.x;
  const int cpx = nwg >> 3;
  const int wg = (blockIdx.x & 7) * cpx + (blockIdx.x >> 3);
  const int bx = wg % NBX, by = wg / NBX;
  const long bm = (long)by * 128;
  const int bn = bx * 256;

  const int scr = tid >> 2, sls = tid & 3;
  const int akU = ((sls ^ (scr & 3) ^ ((scr >> 2) & 3))) * 8;
  const ushort* asrc = A + (bm + scr) * (long)LDA + akU;
  const int rbe = (scr & 31) + ((scr >> 5) << 6);
  const ushort* besrc = W + (long)(bn + rbe) * KK + akU;
  const ushort* bosrc = W + (long)(bn + rbe + 32) * KK + akU;

#define STG(b_, Tt) { \
    gload16(asrc + (Tt) * 32, &lds[b_][tid * 8]); \
    gload16(besrc + (Tt) * 32, &lds[b_][4096 + tid * 8]); \
    gload16(bosrc + (Tt) * 32, &lds[b_][8192 + tid * 8]); }

  STG(0, 0);
  STG(1, 1);

  f4v acc[4][4] = {};

  const int L = lane & 15, q = lane >> 4;
  const int soff = (q ^ (lane & 3) ^ ((lane >> 2) & 3)) * 8;
  const int abase = (wm * 64 + L) * 32 + soff;
  const int bbase = 4096 + (wn * 32 + L) * 32 + soff;

  asm volatile("s_waitcnt vmcnt(3)" ::: "memory");
  asm volatile("s_barrier" ::: "memory");

  for (int T = 0; T < NT; ++T) {
    const ushort* Lp = &lds[T % 3][0];
    bf8v aR[4], bR[4];
    #pragma unroll
    for (int m = 0; m < 4; ++m) aR[m] = *(const bf8v*)(Lp + abase + m * 512);
    bR[0] = *(const bf8v*)(Lp + bbase);
    bR[1] = *(const bf8v*)(Lp + bbase + 512);
    bR[2] = *(const bf8v*)(Lp + bbase + 4096);
    bR[3] = *(const bf8v*)(Lp + bbase + 4096 + 512);
    if (T + 2 < NT) {
      STG((T + 2) % 3, T + 2);
      asm volatile("s_waitcnt vmcnt(3)" ::: "memory");
    } else {
      asm volatile("s_waitcnt vmcnt(0)" ::: "memory");
    }
    asm volatile("s_barrier" ::: "memory");
    __builtin_amdgcn_s_setprio(1);
    #pragma unroll
    for (int m = 0; m < 4; ++m)
      #pragma unroll
      for (int n = 0; n < 4; ++n)
        MFMA_(acc[m][n], aR[m], bR[n]);
    __builtin_amdgcn_s_setprio(0);
  }
#undef STG

  const int colb = bn + wn * 64 + L;
  const long rowb = bm + wm * 64 + q * 4;
  const float* biasp = bias + ((bm >> 13) << 9);
  #pragma unroll
  for (int m = 0; m < 4; ++m) {
    #pragma unroll
    for (int j = 0; j < 4; ++j) {
      const long row = rowb + m * 16 + j;
      #pragma unroll
      for (int n = 0; n < 4; ++n) {
        const int col = colb + n * 16;
        float v = acc[m][n][j] + biasp[col];
        const long idx = row * (long)NN + col;
        ((ushort*)Out)[idx] = f2bf(v + ((const float*)resid)[idx]);
      }
    }
  }
}

// ======== fp8 x fp8 GEMM (non-MX, proven r11): W1 only ====================
// EPI 7: fp8-il out (channel-permuted W1F) = fp8(gelu(acc/8 + b1p))
template<int EPI, int NN, int KK>
__global__ __launch_bounds__(512, 4) void gemmF8(
    const unsigned char* __restrict__ A, const unsigned char* __restrict__ W,
    const float* __restrict__ bias, const void* __restrict__ resid,
    const float* __restrict__ mask, void* __restrict__ Out)
{
  constexpr int NBX = NN / 256;
  constexpr int NT = KK / 64;
  __shared__ __align__(16) unsigned char lds8[3][24576];
  const int tid = threadIdx.x;
  const int lane = tid & 63;
  const int w = tid >> 6;
  const int wm = w >> 2, wn = w & 3;

  const int nwg = gridDim.x;
  const int cpx = nwg >> 3;
  const int wg = (blockIdx.x & 7) * cpx + (blockIdx.x >> 3);
  const int bx = wg % NBX, by = wg / NBX;
  const long bm = (long)by * 128;
  const int bn = bx * 256;

  const int srow = tid >> 2;
  const int sgu = (tid & 3) ^ ((srow >> 1) & 3);
  const unsigned char* asrc = A + (bm + srow) * (long)KK + sgu * 16;
  const unsigned char* b0src = W + (long)(bn + srow) * KK + sgu * 16;
  const unsigned char* b1src = W + (long)(bn + 128 + srow) * KK + sgu * 16;

#define STG8(bf_, Tt) { \
    gload16(asrc + (Tt) * 64, &lds8[bf_][tid * 16]); \
    gload16(b0src + (Tt) * 64, &lds8[bf_][8192 + tid * 16]); \
    gload16(b1src + (Tt) * 64, &lds8[bf_][16384 + tid * 16]); }

  STG8(0, 0);
  STG8(1, 1);

  f4v acc[4][4] = {};

  const int L = lane & 15, q = lane >> 4;
  const int ua = (q ^ ((L >> 1) & 3)) * 16;
  const int arow = (wm * 64 + L) * 64;
  const int brow = 8192 + (wn * 64 + L) * 64;

  asm volatile("s_waitcnt vmcnt(3)" ::: "memory");
  asm volatile("s_barrier" ::: "memory");

  for (int T = 0; T < NT; ++T) {
    const unsigned char* Lp = &lds8[T % 3][0];
    l2v aV[4], bV[4];
    #pragma unroll
    for (int m = 0; m < 4; ++m) aV[m] = *(const l2v*)(Lp + arow + m * 1024 + ua);
    #pragma unroll
    for (int n = 0; n < 4; ++n) bV[n] = *(const l2v*)(Lp + brow + n * 1024 + ua);
    if (T + 2 < NT) {
      STG8((T + 2) % 3, T + 2);
      asm volatile("s_waitcnt vmcnt(3)" ::: "memory");
    } else {
      asm volatile("s_waitcnt vmcnt(0)" ::: "memory");
    }
    asm volatile("s_barrier" ::: "memory");
    __builtin_amdgcn_s_setprio(1);
    #pragma unroll
    for (int m = 0; m < 4; ++m)
      #pragma unroll
      for (int n = 0; n < 4; ++n) {
        acc[m][n] = __builtin_amdgcn_mfma_f32_16x16x32_fp8_fp8(
            aV[m][0], bV[n][0], acc[m][n], 0, 0, 0);
        acc[m][n] = __builtin_amdgcn_mfma_f32_16x16x32_fp8_fp8(
            aV[m][1], bV[n][1], acc[m][n], 0, 0, 0);
      }
    __builtin_amdgcn_s_setprio(0);
  }
#undef STG8

  const long rowb = bm + wm * 64 + q * 4;
  const int gbase = bn + wn * 64;
  if constexpr (EPI == 7) {
    const float4 bp4 = *(const float4*)(bias + gbase + 4 * L);
    #pragma unroll
    for (int m = 0; m < 4; ++m) {
      #pragma unroll
      for (int j = 0; j < 4; ++j) {
        const long row = rowb + m * 16 + j;
        float e0 = gelu_f(acc[m][0][j] * 0.125f + bp4.x);
        float e1 = gelu_f(acc[m][1][j] * 0.125f + bp4.y);
        float e2 = gelu_f(acc[m][2][j] * 0.125f + bp4.z);
        float e3 = gelu_f(acc[m][3][j] * 0.125f + bp4.w);
        unsigned int pw;
#if __has_builtin(__builtin_amdgcn_cvt_pk_fp8_f32)
        int t0 = __builtin_amdgcn_cvt_pk_fp8_f32(e0, e1, 0, false);
        pw = (unsigned int)__builtin_amdgcn_cvt_pk_fp8_f32(e2, e3, t0, true);
#else
        pw = (unsigned int)f2fp8(e0) | ((unsigned int)f2fp8(e1) << 8)
           | ((unsigned int)f2fp8(e2) << 16) | ((unsigned int)f2fp8(e3) << 24);
#endif
        *(unsigned int*)((unsigned char*)Out + row * (long)NN + gbase + 4 * L) = pw;
      }
    }
  } else {
    #pragma unroll
    for (int m = 0; m < 4; ++m) {
      #pragma unroll
      for (int j = 0; j < 4; ++j) {
        const long row = rowb + m * 16 + j;
        const float mk = mask[row];
        #pragma unroll
        for (int n = 0; n < 4; ++n) {
          const int col = gbase + n * 16 + L;
          float v = acc[m][n][j] * 0.125f + bias[col];
          const long idx = row * (long)NN + col;
          ((float*)Out)[idx] =
              (bf2f(((const ushort*)resid)[idx]) + gelu_f(v)) * mk;
        }
      }
    }
  }
}

// ======== W2 MX GEMM: 128x128 tile, K=128 mfma_scale, QUAD-buffered =======
// 4 LDS buffers (64KB; 2 blocks/CU = 128KB), prefetch 3 tiles ahead,
// steady-state vmcnt(4) -> a tile's loads get ~3 barrier intervals (~1800cy)
// to cover HBM latency. acc[4][2]+aOp[4]+bOp[2] ~= 105 VGPR, no spill.
__global__ __launch_bounds__(512, 4) void gemmF8MX2(
    const unsigned char* __restrict__ A, const unsigned char* __restrict__ W,
    const float* __restrict__ bias, const ushort* __restrict__ resid,
    const float* __restrict__ mask, float* __restrict__ Out)
{
  constexpr int NN = 512, KK = 2048;
  constexpr int NBX = 4;
  constexpr int NT = KK / 64;        // 32 tiles, 16 pairs
  __shared__ __align__(16) unsigned char lds8[4][16384];
  const int tid = threadIdx.x;
  const int lane = tid & 63;
  const int w = tid >> 6;
  const int wm = w >> 2, wn = w & 3;   // 2M x 4N waves; per-wave 64x32

  const int nwg = gridDim.x;
  const int cpx = nwg >> 3;
  const int wg = (blockIdx.x & 7) * cpx + (blockIdx.x >> 3);
  const int bx = wg % NBX, by = wg / NBX;
  const long bm = (long)by * 128;
  const int bn = bx * 128;

  const int srow = tid >> 2;
  const int sgu = (tid & 3) ^ ((srow >> 1) & 3);
  const unsigned char* asrc = A + (bm + srow) * (long)KK + sgu * 16;
  const unsigned char* bsrc = W + (long)(bn + srow) * KK + sgu * 16;

#define STGX(bf_, Tt) { \
    gload16(asrc + (Tt) * 64, &lds8[bf_][tid * 16]); \
    gload16(bsrc + (Tt) * 64, &lds8[bf_][8192 + tid * 16]); }

  STGX(0, 0);
  STGX(1, 1);
  STGX(2, 2);

  f4v acc[4][2] = {};
  const int L = lane & 15, q = lane >> 4;
  const int ua = (q ^ ((L >> 1) & 3)) * 16;
  const int arow = (wm * 64 + L) * 64;           // + m*1024
  const int brow = 8192 + (wn * 32 + L) * 64;    // + n*1024

  asm volatile("s_waitcnt vmcnt(4)" ::: "memory");
  asm volatile("s_barrier" ::: "memory");

  l4v aOp[4], bOp[2];
  for (int T2 = 0; T2 < NT / 2; ++T2) {
    {
      const int T = 2 * T2;
      const unsigned char* Lp = &lds8[T & 3][0];
      #pragma unroll
      for (int m = 0; m < 4; ++m) {
        l2v r = *(const l2v*)(Lp + arow + m * 1024 + ua);
        aOp[m][0] = r[0]; aOp[m][1] = r[1];
      }
      #pragma unroll
      for (int n = 0; n < 2; ++n) {
        l2v r = *(const l2v*)(Lp + brow + n * 1024 + ua);
        bOp[n][0] = r[0]; bOp[n][1] = r[1];
      }
      if (T + 3 < NT) {
        STGX((T + 3) & 3, T + 3);
        asm volatile("s_waitcnt vmcnt(4)" ::: "memory");
      } else if (T + 2 < NT) {
        asm volatile("s_waitcnt vmcnt(2)" ::: "memory");
      } else {
        asm volatile("s_waitcnt vmcnt(0)" ::: "memory");
      }
      asm volatile("s_barrier" ::: "memory");
    }
    {
      const int T = 2 * T2 + 1;
      const unsigned char* Lp = &lds8[T & 3][0];
      #pragma unroll
      for (int m = 0; m < 4; ++m) {
        l2v r = *(const l2v*)(Lp + arow + m * 1024 + ua);
        aOp[m][2] = r[0]; aOp[m][3] = r[1];
      }
      #pragma unroll
      for (int n = 0; n < 2; ++n) {
        l2v r = *(const l2v*)(Lp + brow + n * 1024 + ua);
        bOp[n][2] = r[0]; bOp[n][3] = r[1];
      }
      if (T + 3 < NT) {
        STGX((T + 3) & 3, T + 3);
        asm volatile("s_waitcnt vmcnt(4)" ::: "memory");
      } else if (T + 2 < NT) {
        asm volatile("s_waitcnt vmcnt(2)" ::: "memory");
      } else {
        asm volatile("s_waitcnt vmcnt(0)" ::: "memory");
      }
      asm volatile("s_barrier" ::: "memory");
      __builtin_amdgcn_s_setprio(1);
      #pragma unroll
      for (int m = 0; m < 4; ++m) {
        const i8x am = __builtin_bit_cast(i8x, aOp[m]);
        #pragma unroll
        for (int n = 0; n < 2; ++n) {
          acc[m][n] = __builtin_amdgcn_mfma_scale_f32_16x16x128_f8f6f4(
              am, __builtin_bit_cast(i8x, bOp[n]), acc[m][n],
              0, 0, 0, 0x7F7F7F7F, 0, 0x7F7F7F7F);
        }
      }
      __builtin_amdgcn_s_setprio(0);
    }
  }
#undef STGX

  const long rowb = bm + wm * 64 + q * 4;
  const int gbase = bn + wn * 32;
  #pragma unroll
  for (int m = 0; m < 4; ++m) {
    #pragma unroll
    for (int j = 0; j < 4; ++j) {
      const long row = rowb + m * 16 + j;
      const float mk = mask[row];
      #pragma unroll
      for (int n = 0; n < 2; ++n) {
        const int col = gbase + n * 16 + L;
        float v = acc[m][n][j] * 0.125f + bias[col];
        const long idx = row * (long)NN + col;
        Out[idx] = (bf2f(resid[idx]) + gelu_f(v)) * mk;
      }
    }
  }
}

// ---------------- host ----------------
extern "C" void kernel_launch(void* const* d_in, const int* in_sizes, int n_in,
                              void* d_out, int out_size, void* d_ws, size_t ws_size,
                              hipStream_t stream) {
  const float* x    = (const float*)d_in[0];
  const float* mask = (const float*)d_in[1];
  const float* Wq   = (const float*)d_in[2];
  const float* bq   = (const float*)d_in[3];
  const float* Wk   = (const float*)d_in[4];
  const float* bk   = (const float*)d_in[5];
  const float* Wv   = (const float*)d_in[6];
  const float* bv   = (const float*)d_in[7];
  const float* qa   = (const float*)d_in[8];
  const float* kb   = (const float*)d_in[9];
  const float* Wo   = (const float*)d_in[10];
  const float* bo   = (const float*)d_in[11];
  const float* g0   = (const float*)d_in[12];
  const float* be0  = (const float*)d_in[13];
  const float* g1   = (const float*)d_in[14];
  const float* be1  = (const float*)d_in[15];
  const float* W1   = (const float*)d_in[16];
  const float* b1   = (const float*)d_in[17];
  const float* W2   = (const float*)d_in[18];
  const float* b2   = (const float*)d_in[19];
  float* out = (float*)d_out;

  const int M = 65536;          // B*N
  char* ws = (char*)d_ws;
  const size_t MB = 1024 * 1024;
  ushort* XN  = (ushort*)(ws);                           // [0,64) bf16 ln0 out
  ushort* X1  = (ushort*)(ws + 64 * MB);                 // [64,128) bf16
  unsigned char* XN1F = (unsigned char*)(ws + 128 * MB); // [128,160) fp8 il
  unsigned char* H1F  = (unsigned char*)(ws + 192 * MB); // [192,320) fp8 il
  float*  AL  = (float*)(ws + 320 * MB);                 // 2MB
  float*  BL  = (float*)(ws + 322 * MB);                 // 2MB
  float*  PART= (float*)(ws + 324 * MB);                 // 8MB
  char* base = ws + 448 * MB;
  unsigned char* W1F = (unsigned char*)(base);           // 1MB
  unsigned char* W2F = (unsigned char*)(base + 2 * MB);  // 1MB
  ushort* WqoB = (ushort*)(base + 4 * MB);
  float*  WqT  = (float*)(base + 4 * MB + 512 * 1024);
  float*  WvT  = (float*)(base + 5 * MB + 512 * 1024);
  ushort* waB  = (ushort*)(base + 6 * MB + 512 * 1024);
  ushort* wbB  = (ushort*)(base + 6 * MB + 528 * 1024);
  float*  ca   = (float*)(base + 6 * MB + 656 * 1024);
  float*  cbs  = (float*)(base + 6 * MB + 660 * 1024);
  float*  GVB  = (float*)(base + 6 * MB + 920 * 1024);
  float*  BO2  = (float*)(base + 6 * MB + 936 * 1024);
  float*  B1P  = (float*)(base + 6 * MB + 952 * 1024);   // 8KB

  // ---- weight precompute ----
  cvt_w1_fp8il<<<1024, 256, 0, stream>>>(W1, W1F);
  perm_b1<<<8, 256, 0, stream>>>(b1, B1P);
  cvt_f32_fp8il<<<1024, 256, 0, stream>>>(W2, W2F, 1048576, 2047);
  wqo_kernel<<<64, 256, 0, stream>>>(Wo, Wq, WqoB);
  wa_kernel<<<16, 256, 0, stream>>>(qa, Wq, bq, waB, ca);
  transpose512<<<256, 256, 0, stream>>>(Wq, WqT);
  transpose512<<<256, 256, 0, stream>>>(Wv, WvT);

  // ---- fused LN0 (+mask) + alpha logits ----
  ln0_alpha<<<M / 16, 256, 0, stream>>>(x, g0, be0, mask, waB, ca, XN, AL);

  // ---- stage 1: softmax -> pooled x -> gq/wb ----
  softmax_rows<<<64, 1024, 0, stream>>>(AL);
  pool_w<<<512, 256, 0, stream>>>(XN, AL, PART);
  combine_prep1<<<64, 256, 0, stream>>>(PART, WqT, bq, kb, Wk, bk, wbB, cbs);

  // ---- stage 2: beta logits -> softmax -> pooled x -> gv ----
  logits_k<8192, 16><<<1024, 256, 0, stream>>>(XN, wbB, cbs, mask, BL);
  softmax_rows<<<64, 1024, 0, stream>>>(BL);
  pool_w<<<512, 256, 0, stream>>>(XN, BL, PART);
  combine_prep2<<<64, 256, 0, stream>>>(PART, WvT, bv, bq, GVB);
  bias_gv<<<dim3(8, 2), 256, 0, stream>>>(GVB, Wo, bo, BO2);

  // ---- attention out: X1(bf16) = xn @ Wqo^T + BO2[b] + x ----
  gemmP<5, 512, 512, 512><<<2 * (M / 128), 512, 0, stream>>>(
      XN, WqoB, BO2, x, nullptr, X1);

  // ---- LN1 -> XN1F (fp8, k-interleaved) ----
  ln_rows_fp8il<<<M / 4, 256, 0, stream>>>(X1, g1, be1, XN1F);

  // ---- MLP: W1 (non-MX) -> H1F; W2 (MX K=128, quad-buffered) -> out ----
  gemmF8<7, 2048, 512><<<8 * (M / 128), 512, 0, stream>>>(
      XN1F, W1F, B1P, nullptr, nullptr, H1F);
  gemmF8MX2<<<4 * (M / 128), 512, 0, stream>>>(
      H1F, W2F, b2, X1, mask, out);
}